// Round 9
// baseline (176.239 us; speedup 1.0000x reference)
//
#include <hip/hip_runtime.h>

typedef unsigned short ushort;
typedef unsigned int uint;

constexpr int B = 2, C = 64, H = 112, W = 112;
constexpr int HW = H * W;          // 12544
constexpr int NBLK = 512;          // 2 images x 16x16 tiles of 7x7 -> exactly 2 blocks/CU
constexpr float EPS_LN = 1e-6f, EPS_NORM = 1e-7f;

typedef __attribute__((ext_vector_type(8))) short bf16x8;   // 8 bf16 = 4 VGPRs
typedef __attribute__((ext_vector_type(4))) float f32x4;

__device__ __forceinline__ float rcp_fast(float x) { return __builtin_amdgcn_rcpf(x); }
__device__ __forceinline__ float sigmoid_f(float x) { return rcp_fast(1.f + __expf(-x)); }
__device__ __forceinline__ int uni(int x) { return __builtin_amdgcn_readfirstlane(x); }
__device__ __forceinline__ int div7s(int x)  { return (x * 9363) >> 16; }   // exact for 0<=x<64
__device__ __forceinline__ int div13s(int x) { return (x * 5042) >> 16; }   // exact for 0<=x<169
__device__ __forceinline__ int div49s(int x) { return (x * 1338) >> 16; }   // exact for 0<=x<2520

// f32 -> bf16 bits (round-nearest-even) + pair pack/unpack.
__device__ __forceinline__ ushort rne16(float x) {
    uint u = __float_as_uint(x);
    u += 0x7fffu + ((u >> 16) & 1u);
    return (ushort)(u >> 16);
}
__device__ __forceinline__ uint pack2(float a, float b) {
    return (uint)rne16(a) | ((uint)rne16(b) << 16);
}
__device__ __forceinline__ float2 up2(uint u) {
    return make_float2(__uint_as_float(u << 16), __uint_as_float(u & 0xffff0000u));
}

__device__ __forceinline__ f32x4 mfma16(bf16x8 a, bf16x8 b, f32x4 c) {
    return __builtin_amdgcn_mfma_f32_16x16x32_bf16(a, b, c, 0, 0, 0);
}

// XCD-patch swizzle: neighboring tiles share an XCD L2.
__device__ __forceinline__ void decode_blk(int blk, int& b, int& ty, int& tx) {
    int p8 = blk & 7, i = blk >> 3;          // i in [0,64)
    b = p8 >> 2;
    int quad = p8 & 3;
    int lty = i >> 3, ltx = i & 7;           // 8x8 tiles per quadrant
    ty = (quad >> 1) * 8 + lty;              // [0,16)
    tx = (quad & 1) * 8 + ltx;
}

// Split-bf16 GEMM helpers (r6). Weights [64][72] bf16 hi/lo.
__device__ __forceinline__ void stage_w(const float* __restrict__ wsrc,
                                        ushort* wh, ushort* wl, int tid)
{
#pragma unroll
    for (int i = 0; i < 8; ++i) {
        int idx2 = i * 256 + tid;            // 2048 float pairs = 64x64
        int o = idx2 >> 5, k = (idx2 & 31) * 2;
        float2 xy = *(const float2*)&wsrc[o * 64 + k];
        uint h = pack2(xy.x, xy.y);
        *(uint*)&wh[o * 72 + k] = h;
        *(uint*)&wl[o * 72 + k] = pack2(xy.x - __uint_as_float((h & 0xffffu) << 16),
                                        xy.y - __uint_as_float(h & 0xffff0000u));
    }
}

// D(64 x col pp) = W . X(:,pp) + bias. acc[4] of f32x4 covers 16 rows/lane.
__device__ __forceinline__ void gemm64(const ushort* __restrict__ wh, const ushort* __restrict__ wl,
                                       const ushort* __restrict__ xh, const ushort* __restrict__ xl,
                                       const float* __restrict__ bias,
                                       int lm, int l4, int pp, f32x4 acc[4])
{
#pragma unroll
    for (int mt = 0; mt < 4; ++mt) {
        const int ob = mt * 16 + l4 * 4;
        acc[mt][0] = bias[ob]; acc[mt][1] = bias[ob + 1];
        acc[mt][2] = bias[ob + 2]; acc[mt][3] = bias[ob + 3];
    }
#pragma unroll
    for (int kt = 0; kt < 2; ++kt) {
        const int xo = pp * 72 + kt * 32 + l4 * 8;
        bf16x8 bh = *(const bf16x8*)&xh[xo];
        bf16x8 bl = *(const bf16x8*)&xl[xo];
#pragma unroll
        for (int mt = 0; mt < 4; ++mt) {
            const int wo = (mt * 16 + lm) * 72 + kt * 32 + l4 * 8;
            bf16x8 ah = *(const bf16x8*)&wh[wo];
            bf16x8 al = *(const bf16x8*)&wl[wo];
            acc[mt] = mfma16(al, bh, acc[mt]);
            acc[mt] = mfma16(ah, bl, acc[mt]);
            acc[mt] = mfma16(ah, bh, acc[mt]);
        }
    }
}

// ---------------------------------------------------------------------------
// r9: ONE ordinary kernel. Each block computes range_proj for ALL 169 halo
// pixels locally (3.4x redundant MFMA work, but removes the k1 dispatch, the
// px16/sqnorm global round-trip, and every cross-block dependency — r8's
// cooperative launch failed under graph capture). Numerics bit-identical to
// r7 (same staging splits, same gemm64, same rne16 px quantization, same f32
// sqnorm/dmat). Out-of-image halo pixels forced to px=0/sqn=0 (reference
// zero-pad semantics). LDS: 70144 B arena, lifetime-multiplexed.
// ---------------------------------------------------------------------------
__global__ __launch_bounds__(256, 2) void k_fused(
    const float* __restrict__ sem,  const float* __restrict__ spat,
    const float* __restrict__ rw1, const float* __restrict__ rb1,
    const float* __restrict__ rg,  const float* __restrict__ rbe,
    const float* __restrict__ rw2, const float* __restrict__ rb2,
    const float* __restrict__ fw1, const float* __restrict__ fb1,
    const float* __restrict__ fg,  const float* __restrict__ fbe,
    const float* __restrict__ fw2, const float* __restrict__ fb2,
    const float* __restrict__ w1, const float* __restrict__ b1,
    const float* __restrict__ g,  const float* __restrict__ be,
    const float* __restrict__ w2, const float* __restrict__ b2,
    const float* __restrict__ sigma_, float* __restrict__ out)
{
    __shared__ __align__(16) float smem[17536];          // 70144 B arena
    // ---- Phase A (range_proj on 176 halo pixels) ----
    ushort* whA = (ushort*)smem;                         // [64][72] hi  fl [0,2304)
    ushort* wlA = (ushort*)smem + 4608;                  // lo           fl [2304,4608)
    ushort* xhA = (ushort*)(smem + 4608);                // [176][72] hi fl [4608,10944)
    ushort* xlA = (ushort*)(smem + 4608) + 12672;        // lo           fl [10944,17280)
    float*  bvA = smem + 17280;                          // 256          fl [17280,17536)
    // ---- Phase A->B handoff ----
    ushort* haloA = (ushort*)smem;                       // [169][64] swizzled fl [0,5408)
    float*  sqn_l = smem + 5408;                         // 169 fl [5408,5577)
    float*  dmat  = smem + 5616;                         // [176][66] f32 fl [5616,17232)
    // ---- Phase B ----
    float*  fwc   = smem;                                // 2401 fl [0,2401)
    float*  fw2l  = smem + 2401;                         // 2401 fl [2401,4802)
    float*  comb  = smem + 4802;                         // 3136 fl [4802,7938)
    ushort* haloB = (ushort*)(smem + 7938);              // [169][64] fl [7938,13346)
    float*  fscr  = smem + 13346;                        // 3136 fl [13346,16482)
    float*  pm3   = smem + 16482;                        // 256
    float*  ps3   = smem + 16738;                        // 256
    float*  pt    = smem + 16994;                        // 256 -> 17250
    // P5/P6 overlays:
    ushort* whiP = (ushort*)smem;                        // op W hi fl [0,2304)
    ushort* wloP = (ushort*)smem + 4608;                 // lo      fl [2304,4608)
    float*  bvP  = smem + 16482;                         // 256 over dead pm3
    ushort* ahiP = (ushort*)(smem + 4802);               // act hi fl [4802,7106)
    ushort* aloP = (ushort*)(smem + 4802) + 4608;        // lo     fl [7106,9410)

    const int tid = threadIdx.x, lane = tid & 63, wv = tid >> 6;
    const int lm = lane & 15, l4 = lane >> 4;
    int b, ty, tx; decode_blk(blockIdx.x, b, ty, tx);
    const int lp  = lane < 49 ? lane : 48;
    const int py  = div7s(lp), pxl = lp - py * 7;
    const int h = ty * 7 + py, w = tx * 7 + pxl;
    const int hw = h * W + w;
    const int h0 = ty * 7 - 3, w0 = tx * 7 - 3;
    const bool act = lane < 49;
    const int pp = wv * 16 + lm;

    // ================= PHASE A: range_proj on the halo =================
    // stage X halo (sem -> split bf16 [176][72]); rows>=169 and out-of-image
    // rows are zero.
    if (tid < 176) {
        const int r = tid;
        bool valid = false; int soff = 0;
        if (r < 169) {
            int ry = div13s(r), rx = r - ry * 13;
            int hh = h0 + ry, ww = w0 + rx;
            valid = (unsigned)hh < (unsigned)H && (unsigned)ww < (unsigned)W;
            soff = hh * W + ww;
        }
#pragma unroll
        for (int cq = 0; cq < 8; ++cq) {
            float x[8];
#pragma unroll
            for (int j = 0; j < 8; ++j)
                x[j] = valid ? sem[(size_t)(b * 64 + cq * 8 + j) * HW + soff] : 0.f;
            uint hu[4], lu[4];
#pragma unroll
            for (int j = 0; j < 4; ++j) {
                uint hh2 = pack2(x[2 * j], x[2 * j + 1]);
                hu[j] = hh2;
                lu[j] = pack2(x[2 * j]     - __uint_as_float((hh2 & 0xffffu) << 16),
                              x[2 * j + 1] - __uint_as_float(hh2 & 0xffff0000u));
            }
            *(uint4*)&xhA[r * 72 + cq * 8] = make_uint4(hu[0], hu[1], hu[2], hu[3]);
            *(uint4*)&xlA[r * 72 + cq * 8] = make_uint4(lu[0], lu[1], lu[2], lu[3]);
        }
    }
    stage_w(rw1, whA, wlA, tid);
    if (tid < 64) { bvA[tid] = rb1[tid]; bvA[64 + tid] = rg[tid];
                    bvA[128 + tid] = rbe[tid]; bvA[192 + tid] = rb2[tid]; }
    __syncthreads();

    // conv1 + LN + SiLU, write s back over own X columns (wave-owned cols)
#pragma unroll
    for (int i = 0; i < 3; ++i) {
        const int nt = wv + 4 * i;
        if (nt < 11) {
            const int p = nt * 16 + lm;
            f32x4 f1[4];
            gemm64(whA, wlA, xhA, xlA, bvA, lm, l4, p, f1);
            float psum = 0.f, psq = 0.f;
#pragma unroll
            for (int mt = 0; mt < 4; ++mt)
#pragma unroll
                for (int r = 0; r < 4; ++r) { float fv = f1[mt][r]; psum += fv; psq += fv * fv; }
            psum += __shfl_xor(psum, 16); psum += __shfl_xor(psum, 32);
            psq  += __shfl_xor(psq, 16);  psq  += __shfl_xor(psq, 32);
            const float m = psum * (1.f / 64.f);
            const float rstd = rsqrtf(psq * (1.f / 64.f) - m * m + EPS_LN);
#pragma unroll
            for (int mt = 0; mt < 4; ++mt) {
                float s0, s1, s2, s3;
                {
                    const int o = mt * 16 + l4 * 4;
                    float y0 = bvA[64 + o]     * (f1[mt][0] - m) * rstd + bvA[128 + o];
                    float y1 = bvA[64 + o + 1] * (f1[mt][1] - m) * rstd + bvA[128 + o + 1];
                    float y2 = bvA[64 + o + 2] * (f1[mt][2] - m) * rstd + bvA[128 + o + 2];
                    float y3 = bvA[64 + o + 3] * (f1[mt][3] - m) * rstd + bvA[128 + o + 3];
                    s0 = y0 * sigmoid_f(y0); s1 = y1 * sigmoid_f(y1);
                    s2 = y2 * sigmoid_f(y2); s3 = y3 * sigmoid_f(y3);
                }
                uint h0_ = pack2(s0, s1), h1_ = pack2(s2, s3);
                uint l0_ = pack2(s0 - __uint_as_float((h0_ & 0xffffu) << 16),
                                 s1 - __uint_as_float(h0_ & 0xffff0000u));
                uint l1_ = pack2(s2 - __uint_as_float((h1_ & 0xffffu) << 16),
                                 s3 - __uint_as_float(h1_ & 0xffff0000u));
                const int so = p * 72 + mt * 16 + l4 * 4;
                *(uint2*)&xhA[so] = make_uint2(h0_, h1_);
                *(uint2*)&xlA[so] = make_uint2(l0_, l1_);
            }
        }
    }
    __syncthreads();
    stage_w(rw2, whA, wlA, tid);    // restage W2 over W1 strip
    __syncthreads();

    // conv2; stash packed z + sqnorm in registers (W/X strips die at barrier)
    uint zpk[24];
    float sqs[3];
#pragma unroll
    for (int i = 0; i < 3; ++i) {
        const int nt = wv + 4 * i;
        if (nt < 11) {
            const int p = nt * 16 + lm;
            f32x4 z1[4];
            gemm64(whA, wlA, xhA, xlA, bvA + 192, lm, l4, p, z1);
            float sq = 0.f;
#pragma unroll
            for (int mt = 0; mt < 4; ++mt)
#pragma unroll
                for (int r = 0; r < 4; ++r) sq += z1[mt][r] * z1[mt][r];
            sq += __shfl_xor(sq, 16); sq += __shfl_xor(sq, 32);
            sqs[i] = sq;
#pragma unroll
            for (int mt = 0; mt < 4; ++mt) {
                zpk[i * 8 + 2 * mt]     = pack2(z1[mt][0], z1[mt][1]);
                zpk[i * 8 + 2 * mt + 1] = pack2(z1[mt][2], z1[mt][3]);
            }
        }
    }
    __syncthreads();   // all W2/X reads done -> haloA/sqn region writable

    // write px halo (bf16, XOR-swizzled rows) + sqnorm; zeros outside image
#pragma unroll
    for (int i = 0; i < 3; ++i) {
        const int nt = wv + 4 * i;
        const int p = nt * 16 + lm;
        if (nt < 11 && p < 169) {
            int ry = div13s(p), rx = p - ry * 13;
            int hh = h0 + ry, ww = w0 + rx;
            bool valid = (unsigned)hh < (unsigned)H && (unsigned)ww < (unsigned)W;
#pragma unroll
            for (int mt = 0; mt < 4; ++mt) {
                const int ch = mt * 16 + l4 * 4;
                const int q8 = ch >> 3;
                const int off = (p << 6) + ((q8 ^ (p & 7)) << 3) + (ch & 7);
                uint2 v = valid ? make_uint2(zpk[i * 8 + 2 * mt], zpk[i * 8 + 2 * mt + 1])
                                : make_uint2(0u, 0u);
                *(uint2*)&haloA[off] = v;
            }
            if (l4 == 0) sqn_l[p] = valid ? sqs[i] : 0.f;
        }
    }
    // sv gather (P3 input); VMEM latency hides under P2 MFMA + extraction
    float sv[64];
#pragma unroll
    for (int k = 0; k < 64; ++k) sv[k] = sem[(size_t)(b * 64 + k) * HW + hw];
    __syncthreads();

    // ================= PHASE B: bilateral (as r7) =================
    // P2-MFMA: D[hp][p] = <haloA[hp], haloA[rp(p)]> -> dmat f32
    {
        const int qp = pp < 49 ? pp : 48;
        const int pyp = div7s(qp), pxp = qp - pyp * 7;
        const int rpp = pyp * 13 + pxp + 42;
        bf16x8 bc0 = *(const bf16x8*)&haloA[(rpp << 6) + ((l4 ^ (rpp & 7)) << 3)];
        bf16x8 bc1 = *(const bf16x8*)&haloA[(rpp << 6) + (((4 + l4) ^ (rpp & 7)) << 3)];
#pragma unroll
        for (int mt = 0; mt < 11; ++mt) {
            const int r = mt * 16 + lm;
            bf16x8 a0 = *(const bf16x8*)&haloA[(r << 6) + ((l4 ^ (r & 7)) << 3)];
            bf16x8 a1 = *(const bf16x8*)&haloA[(r << 6) + (((4 + l4) ^ (r & 7)) << 3)];
            f32x4 d = {0.f, 0.f, 0.f, 0.f};
            d = mfma16(a0, bc0, d);
            d = mfma16(a1, bc1, d);
            const int orow = mt * 16 + l4 * 4;
#pragma unroll
            for (int rr = 0; rr < 4; ++rr)
                dmat[(orow + rr) * 66 + pp] = d[rr];
        }
    }
    __syncthreads();

    // extraction (wave-split n) into regs; fixup weights -> dead haloA strip
    const int rbase = py * 13 + pxl;
    const int rp = rbase + 42;
    float cbl[13];
    {
        const float sqc = sqn_l[rp];
        const float sg_ = sigma_[0];
        const float inv2s2 = rcp_fast(2.f * sg_ * sg_);
#pragma unroll
        for (int i = 0; i < 13; ++i) {
            const int n = uni(wv + 4 * i);
            cbl[i] = 0.f;
            if (n < 49) {
                int ryn = div7s(n), rxn = n - ryn * 7;
                int dy = ryn - 3, dx = rxn - 3;
                int rn = rbase + ryn * 13 + rxn;
                float dot = dmat[rn * 66 + lane];
                float dist2 = fmaxf(sqn_l[rn] + sqc - 2.f * dot, 0.f);
                bool validn = (unsigned)(h + dy) < (unsigned)H && (unsigned)(w + dx) < (unsigned)W;
                float d2n = (float)(dy * dy + dx * dx);
                cbl[i] = validn ? __expf(-(dist2 * (1.f / 128.f) + d2n * inv2s2)) : 0.f;
            }
        }
    }
    for (int i = tid; i < 2401; i += 256) {       // disjoint from dmat/sqn reads
        int o = div49s(i);
        fwc[i]  = fw1[o * 113 + (i - o * 49)];
        fw2l[i] = fw2[i];
    }
    __syncthreads();   // dmat + sqn dead below

    // write comb; stage spat halo -> haloB (latency hides under P3)
#pragma unroll
    for (int i = 0; i < 13; ++i) {
        const int n = wv + 4 * i;
        if (n < 49) comb[n * 64 + lane] = cbl[i];
    }
    if (tid < 169) {
        const int ry = div13s(tid), rx = tid - ry * 13;
        const int hh = h0 + ry, ww = w0 + rx;
        const bool valid = (unsigned)hh < (unsigned)H && (unsigned)ww < (unsigned)W;
        const int soff = hh * W + ww;
        const int rsw = (tid & 7), rb_ = tid << 6;
#pragma unroll
        for (int cq = 0; cq < 8; ++cq) {
            uint4 v = make_uint4(0u, 0u, 0u, 0u);
            if (valid) {
                const float* sp = &spat[(size_t)(b * 64 + 8 * cq) * HW + soff];
                v.x = pack2(sp[0],      sp[HW]);
                v.y = pack2(sp[2 * HW], sp[3 * HW]);
                v.z = pack2(sp[4 * HW], sp[5 * HW]);
                v.w = pack2(sp[6 * HW], sp[7 * HW]);
            }
            *(uint4*)&haloB[rb_ + ((cq ^ rsw) << 3)] = v;
        }
    }
    __syncthreads();

    // P3: gated fixup (sv in registers)
    {
        float cb[49];
#pragma unroll
        for (int n = 0; n < 49; ++n) cb[n] = comb[n * 64 + lane];
        float macc = 0.f, sacc = 0.f;
        for (int i = 0; i < 13; ++i) {
            const int o = uni(wv + 4 * i);
            if (o < 49) {
                const float* wr = &fwc[o * 49];
                float a0 = 0, a1 = 0, a2 = 0, a3 = 0;
#pragma unroll
                for (int k = 0; k < 48; k += 4) {
                    a0 += wr[k] * cb[k];       a1 += wr[k + 1] * cb[k + 1];
                    a2 += wr[k + 2] * cb[k + 2]; a3 += wr[k + 3] * cb[k + 3];
                }
                a0 += wr[48] * cb[48];
                const float* wr2 = &fw1[o * 113 + 49];   // sem-half via s_load
#pragma unroll
                for (int k = 0; k < 64; k += 4) {
                    a0 += wr2[k] * sv[k];       a1 += wr2[k + 1] * sv[k + 1];
                    a2 += wr2[k + 2] * sv[k + 2]; a3 += wr2[k + 3] * sv[k + 3];
                }
                float f = (a0 + a1) + (a2 + a3) + fb1[o];
                fscr[o * 64 + lane] = f;
                macc += f; sacc += f * f;
            }
        }
        pm3[wv * 64 + lane] = macc; ps3[wv * 64 + lane] = sacc;
    }
    __syncthreads();
    {
        float m  = (pm3[lane] + pm3[64 + lane] + pm3[128 + lane] + pm3[192 + lane]) * (1.f / 49.f);
        float va = (ps3[lane] + ps3[64 + lane] + ps3[128 + lane] + ps3[192 + lane]) * (1.f / 49.f) - m * m;
        float rstd = rsqrtf(va + EPS_LN);
        float s[49];
#pragma unroll
        for (int k = 0; k < 49; ++k) {
            float y = fg[k] * (fscr[k * 64 + lane] - m) * rstd + fbe[k];
            s[k] = y * sigmoid_f(y);
        }
        float tacc = 0.f;
        for (int i = 0; i < 13; ++i) {
            const int o = uni(wv + 4 * i);
            if (o < 49) {
                const float* wr = &fw2l[o * 49];
                float a0 = 0, a1 = 0, a2 = 0, a3 = 0;
#pragma unroll
                for (int k = 0; k < 48; k += 4) {
                    a0 += wr[k] * s[k];       a1 += wr[k + 1] * s[k + 1];
                    a2 += wr[k + 2] * s[k + 2]; a3 += wr[k + 3] * s[k + 3];
                }
                a0 += wr[48] * s[48];
                float fo = (a0 + a1) + (a2 + a3) + fb2[o];
                float gate = 1.f + sigmoid_f(fo);
                float cx = comb[o * 64 + lane] * gate;   // own rows: no race
                comb[o * 64 + lane] = cx;
                tacc += cx;
            }
        }
        pt[wv * 64 + lane] = tacc;
    }
    __syncthreads();
    const float inv = rcp_fast(pt[lane] + pt[64 + lane] + pt[128 + lane] + pt[192 + lane] + EPS_NORM);

    // stage op_w1 (split bf16) over dead fwc/fw2l + bias vec over dead pm3
    stage_w(w1, whiP, wloP, tid);
    if (tid < 64) { bvP[tid] = b1[tid]; bvP[64 + tid] = g[tid];
                    bvP[128 + tid] = be[tid]; bvP[192 + tid] = b2[tid]; }

    // P5: weighted neighborhood reduction (haloB)
    const int c0 = uni(wv * 16);
    const int qq0 = c0 >> 3;
    float acc[16];
#pragma unroll
    for (int j = 0; j < 16; ++j) acc[j] = 0.f;
    for (int n = 0; n < 49; ++n) {
        int ryn = n / 7, rxn = n - ryn * 7;
        int rn = rbase + ryn * 13 + rxn;
        float cn = comb[n * 64 + lane] * inv;
        const int rb_ = rn << 6, rsw = rn & 7;
#pragma unroll
        for (int q = 0; q < 2; ++q) {
            uint4 v = *(const uint4*)&haloB[rb_ + (((qq0 + q) ^ rsw) << 3)];
            float2 a = up2(v.x), bb = up2(v.y), c = up2(v.z), d = up2(v.w);
            acc[8 * q + 0] += cn * a.x;  acc[8 * q + 1] += cn * a.y;
            acc[8 * q + 2] += cn * bb.x; acc[8 * q + 3] += cn * bb.y;
            acc[8 * q + 4] += cn * c.x;  acc[8 * q + 5] += cn * c.y;
            acc[8 * q + 6] += cn * d.x;  acc[8 * q + 7] += cn * d.y;
        }
    }
    __syncthreads();   // comb/haloB reads done; whiP/bvP staging visible

    // P6a: write P5 result as split-bf16 activations [pixel][72]
    {
        uint hu[8], lu[8];
#pragma unroll
        for (int jj = 0; jj < 8; ++jj) {
            float x0 = act ? acc[2 * jj] : 0.f;
            float x1 = act ? acc[2 * jj + 1] : 0.f;
            uint hh = pack2(x0, x1);
            hu[jj] = hh;
            lu[jj] = pack2(x0 - __uint_as_float((hh & 0xffffu) << 16),
                           x1 - __uint_as_float(hh & 0xffff0000u));
        }
        const int rb = lane * 72 + c0;
        *(uint4*)&ahiP[rb]     = make_uint4(hu[0], hu[1], hu[2], hu[3]);
        *(uint4*)&ahiP[rb + 8] = make_uint4(hu[4], hu[5], hu[6], hu[7]);
        *(uint4*)&aloP[rb]     = make_uint4(lu[0], lu[1], lu[2], lu[3]);
        *(uint4*)&aloP[rb + 8] = make_uint4(lu[4], lu[5], lu[6], lu[7]);
    }
    __syncthreads();

    // P6b: conv1 MFMA + LN(shfl)
    f32x4 f6[4];
    gemm64(whiP, wloP, ahiP, aloP, bvP, lm, l4, pp, f6);

    float psum = 0.f, psq = 0.f;
#pragma unroll
    for (int mt = 0; mt < 4; ++mt)
#pragma unroll
        for (int r = 0; r < 4; ++r) { float fv = f6[mt][r]; psum += fv; psq += fv * fv; }
    psum += __shfl_xor(psum, 16); psum += __shfl_xor(psum, 32);
    psq  += __shfl_xor(psq, 16);  psq  += __shfl_xor(psq, 32);
    const float m6 = psum * (1.f / 64.f);
    const float rstd6 = rsqrtf(psq * (1.f / 64.f) - m6 * m6 + EPS_LN);

    float yv[16];
#pragma unroll
    for (int mt = 0; mt < 4; ++mt)
#pragma unroll
        for (int r = 0; r < 4; ++r) {
            const int o = mt * 16 + l4 * 4 + r;
            yv[mt * 4 + r] = bvP[64 + o] * (f6[mt][r] - m6) * rstd6 + bvP[128 + o];
        }
    __syncthreads();   // conv1 fragment reads done -> strips reusable

    // write y (split bf16) over act strip; restage op_w2 over W strip
#pragma unroll
    for (int mt = 0; mt < 4; ++mt) {
        uint h0_ = pack2(yv[4 * mt],     yv[4 * mt + 1]);
        uint h1_ = pack2(yv[4 * mt + 2], yv[4 * mt + 3]);
        uint l0_ = pack2(yv[4 * mt]     - __uint_as_float((h0_ & 0xffffu) << 16),
                         yv[4 * mt + 1] - __uint_as_float(h0_ & 0xffff0000u));
        uint l1_ = pack2(yv[4 * mt + 2] - __uint_as_float((h1_ & 0xffffu) << 16),
                         yv[4 * mt + 3] - __uint_as_float(h1_ & 0xffff0000u));
        const int so = pp * 72 + mt * 16 + l4 * 4;
        *(uint2*)&ahiP[so] = make_uint2(h0_, h1_);
        *(uint2*)&aloP[so] = make_uint2(l0_, l1_);
    }
    stage_w(w2, whiP, wloP, tid);
    __syncthreads();

    // P6c: conv2 MFMA + store
    f32x4 z6[4];
    gemm64(whiP, wloP, ahiP, aloP, bvP + 192, lm, l4, pp, z6);

    if (pp < 49) {
        const int py6 = div7s(pp), px6 = pp - py6 * 7;
        const int hwi6 = (ty * 7 + py6) * W + tx * 7 + px6;
#pragma unroll
        for (int mt = 0; mt < 4; ++mt)
#pragma unroll
            for (int r = 0; r < 4; ++r)
                out[(size_t)(b * 64 + mt * 16 + l4 * 4 + r) * HW + hwi6] = z6[mt][r];
    }
}

extern "C" void kernel_launch(void* const* d_in, const int* in_sizes, int n_in,
                              void* d_out, int out_size, void* d_ws, size_t ws_size,
                              hipStream_t stream)
{
    const float* spatial  = (const float*)d_in[0];
    const float* semantic = (const float*)d_in[1];
    const float* rp_w1 = (const float*)d_in[2];
    const float* rp_b1 = (const float*)d_in[3];
    const float* rp_g  = (const float*)d_in[4];
    const float* rp_be = (const float*)d_in[5];
    const float* rp_w2 = (const float*)d_in[6];
    const float* rp_b2 = (const float*)d_in[7];
    const float* fx_w1 = (const float*)d_in[8];
    const float* fx_b1 = (const float*)d_in[9];
    const float* fx_g  = (const float*)d_in[10];
    const float* fx_be = (const float*)d_in[11];
    const float* fx_w2 = (const float*)d_in[12];
    const float* fx_b2 = (const float*)d_in[13];
    const float* op_w1 = (const float*)d_in[14];
    const float* op_b1 = (const float*)d_in[15];
    const float* op_g  = (const float*)d_in[16];
    const float* op_be = (const float*)d_in[17];
    const float* op_w2 = (const float*)d_in[18];
    const float* op_b2 = (const float*)d_in[19];
    const float* sigma = (const float*)d_in[20];

    k_fused<<<NBLK, 256, 0, stream>>>(
        semantic, spatial,
        rp_w1, rp_b1, rp_g, rp_be, rp_w2, rp_b2,
        fx_w1, fx_b1, fx_g, fx_be, fx_w2, fx_b2,
        op_w1, op_b1, op_g, op_be, op_w2, op_b2,
        sigma, (float*)d_out);
}

// Round 10
// 152.188 us; speedup vs baseline: 1.1580x; 1.1580x over previous
//
#include <hip/hip_runtime.h>

typedef unsigned short ushort;
typedef unsigned int uint;

constexpr int B = 2, C = 64, H = 112, W = 112;
constexpr int HW = H * W;          // 12544
constexpr int NPIX = B * HW;       // 25088
constexpr int NBLK = 512;          // 2 images x 16x16 tiles of 7x7 -> exactly 2 blocks/CU
constexpr float EPS_LN = 1e-6f, EPS_NORM = 1e-7f;

typedef __attribute__((ext_vector_type(8))) short bf16x8;   // 8 bf16 = 4 VGPRs
typedef __attribute__((ext_vector_type(4))) float f32x4;

__device__ __forceinline__ float rcp_fast(float x) { return __builtin_amdgcn_rcpf(x); }
__device__ __forceinline__ float sigmoid_f(float x) { return rcp_fast(1.f + __expf(-x)); }
__device__ __forceinline__ int uni(int x) { return __builtin_amdgcn_readfirstlane(x); }
__device__ __forceinline__ int div7s(int x)  { return (x * 9363) >> 16; }   // exact for 0<=x<64
__device__ __forceinline__ int div13s(int x) { return (x * 5042) >> 16; }   // exact for 0<=x<169

// f32 -> bf16 bits (round-nearest-even) + pair pack/unpack.
__device__ __forceinline__ ushort rne16(float x) {
    uint u = __float_as_uint(x);
    u += 0x7fffu + ((u >> 16) & 1u);
    return (ushort)(u >> 16);
}
__device__ __forceinline__ uint pack2(float a, float b) {
    return (uint)rne16(a) | ((uint)rne16(b) << 16);
}
__device__ __forceinline__ float2 up2(uint u) {
    return make_float2(__uint_as_float(u << 16), __uint_as_float(u & 0xffff0000u));
}
__device__ __forceinline__ float up1(ushort u) {
    return __uint_as_float((uint)u << 16);
}

__device__ __forceinline__ f32x4 mfma16(bf16x8 a, bf16x8 b, f32x4 c) {
    return __builtin_amdgcn_mfma_f32_16x16x32_bf16(a, b, c, 0, 0, 0);
}

// XCD-patch swizzle (BOTH kernels -> producer/consumer share an XCD L2).
__device__ __forceinline__ void decode_blk(int blk, int& b, int& ty, int& tx) {
    int p8 = blk & 7, i = blk >> 3;          // i in [0,64)
    b = p8 >> 2;
    int quad = p8 & 3;
    int lty = i >> 3, ltx = i & 7;           // 8x8 tiles per quadrant
    ty = (quad >> 1) * 8 + lty;              // [0,16)
    tx = (quad & 1) * 8 + ltx;
}

// ---------------------------------------------------------------------------
// Split-bf16 GEMM helpers. Weights/activations [64 rows][72] bf16 hi/lo.
// ---------------------------------------------------------------------------
__device__ __forceinline__ void stage_w(const float* __restrict__ wsrc,
                                        ushort* wh, ushort* wl, int tid)
{
#pragma unroll
    for (int i = 0; i < 8; ++i) {
        int idx2 = i * 256 + tid;            // 2048 float pairs = 64x64
        int o = idx2 >> 5, k = (idx2 & 31) * 2;
        float2 xy = *(const float2*)&wsrc[o * 64 + k];
        uint h = pack2(xy.x, xy.y);
        *(uint*)&wh[o * 72 + k] = h;
        *(uint*)&wl[o * 72 + k] = pack2(xy.x - __uint_as_float((h & 0xffffu) << 16),
                                        xy.y - __uint_as_float(h & 0xffff0000u));
    }
}

// Stage a nrow x ncol (<=64x64) matrix with arbitrary row stride into the
// zero-padded [64][72] hi/lo strips. thread t: row t>>2, col quarter t&3.
__device__ __forceinline__ void stage_wpad(const float* __restrict__ src, int ld,
                                           int nrow, int ncol,
                                           ushort* wh, ushort* wl, int tid)
{
    const int o = tid >> 2, q = (tid & 3) * 16;
#pragma unroll
    for (int jj = 0; jj < 8; ++jj) {
        int c = q + 2 * jj;
        float x0 = (o < nrow && c < ncol)     ? src[o * ld + c]     : 0.f;
        float x1 = (o < nrow && c + 1 < ncol) ? src[o * ld + c + 1] : 0.f;
        uint hh = pack2(x0, x1);
        uint ll = pack2(x0 - __uint_as_float((hh & 0xffffu) << 16),
                        x1 - __uint_as_float(hh & 0xffff0000u));
        *(uint*)&wh[o * 72 + c] = hh;
        *(uint*)&wl[o * 72 + c] = ll;
    }
}

__device__ __forceinline__ void gemm64_acc(const ushort* __restrict__ wh, const ushort* __restrict__ wl,
                                           const ushort* __restrict__ xh, const ushort* __restrict__ xl,
                                           int lm, int l4, int pp, f32x4 acc[4])
{
#pragma unroll
    for (int kt = 0; kt < 2; ++kt) {
        const int xo = pp * 72 + kt * 32 + l4 * 8;
        bf16x8 bh = *(const bf16x8*)&xh[xo];
        bf16x8 bl = *(const bf16x8*)&xl[xo];
#pragma unroll
        for (int mt = 0; mt < 4; ++mt) {
            const int wo = (mt * 16 + lm) * 72 + kt * 32 + l4 * 8;
            bf16x8 ah = *(const bf16x8*)&wh[wo];
            bf16x8 al = *(const bf16x8*)&wl[wo];
            acc[mt] = mfma16(al, bh, acc[mt]);
            acc[mt] = mfma16(ah, bl, acc[mt]);
            acc[mt] = mfma16(ah, bh, acc[mt]);
        }
    }
}

__device__ __forceinline__ void gemm64(const ushort* __restrict__ wh, const ushort* __restrict__ wl,
                                       const ushort* __restrict__ xh, const ushort* __restrict__ xl,
                                       const float* __restrict__ bias,
                                       int lm, int l4, int pp, f32x4 acc[4])
{
#pragma unroll
    for (int mt = 0; mt < 4; ++mt) {
        const int ob = mt * 16 + l4 * 4;
        acc[mt][0] = bias[ob]; acc[mt][1] = bias[ob + 1];
        acc[mt][2] = bias[ob + 2]; acc[mt][3] = bias[ob + 3];
    }
    gemm64_acc(wh, wl, xh, xl, lm, l4, pp, acc);
}

// ---------------------------------------------------------------------------
// k1: px = range_proj(semantic) -> px16[p][64] (bf16) + sqnorm[p].
// Unchanged from r7 (full split-bf16 MFMA; verified; ~7 us).
// ---------------------------------------------------------------------------
__global__ __launch_bounds__(256) void k1_range_proj(
    const float* __restrict__ sem,
    const float* __restrict__ w1, const float* __restrict__ b1,
    const float* __restrict__ g,  const float* __restrict__ be,
    const float* __restrict__ w2, const float* __restrict__ b2,
    ushort* __restrict__ px16, float* __restrict__ sqnorm)
{
    __shared__ __align__(16) ushort u16[28160];   // 56320 B
    ushort* wh1 = u16;                 // [64][72] each (4608 ushorts)
    ushort* wl1 = u16 + 4608;
    ushort* wh2 = u16 + 9216;
    ushort* wl2 = u16 + 13824;
    ushort* xh  = u16 + 18432;         // activations / s (reused)
    ushort* xl  = u16 + 23040;         // ..27648
    float*  bv  = (float*)(u16 + 27648);   // b1|g|be|b2 (256 floats)

    const int tid = threadIdx.x, lane = tid & 63, wv = tid >> 6;
    const int lm = lane & 15, l4 = lane >> 4;
    int b, ty, tx; decode_blk(blockIdx.x, b, ty, tx);

    {
        const int lp = lane < 49 ? lane : 48;
        const int py = div7s(lp), px = lp - py * 7;
        const int hw = (ty * 7 + py) * W + tx * 7 + px;
        const bool a = lane < 49;
        float xv[16];
#pragma unroll
        for (int j = 0; j < 16; ++j)
            xv[j] = a ? sem[(size_t)(b * 64 + wv * 16 + j) * HW + hw] : 0.f;
        uint hu[8], lu[8];
#pragma unroll
        for (int jj = 0; jj < 8; ++jj) {
            uint hh = pack2(xv[2 * jj], xv[2 * jj + 1]);
            hu[jj] = hh;
            lu[jj] = pack2(xv[2 * jj]     - __uint_as_float((hh & 0xffffu) << 16),
                           xv[2 * jj + 1] - __uint_as_float(hh & 0xffff0000u));
        }
        const int rb = lane * 72 + wv * 16;
        *(uint4*)&xh[rb]     = make_uint4(hu[0], hu[1], hu[2], hu[3]);
        *(uint4*)&xh[rb + 8] = make_uint4(hu[4], hu[5], hu[6], hu[7]);
        *(uint4*)&xl[rb]     = make_uint4(lu[0], lu[1], lu[2], lu[3]);
        *(uint4*)&xl[rb + 8] = make_uint4(lu[4], lu[5], lu[6], lu[7]);
    }
    stage_w(w1, wh1, wl1, tid);
    stage_w(w2, wh2, wl2, tid);
    if (tid < 64) { bv[tid] = b1[tid]; bv[64 + tid] = g[tid];
                    bv[128 + tid] = be[tid]; bv[192 + tid] = b2[tid]; }
    __syncthreads();

    const int pp = wv * 16 + lm;
    f32x4 f[4];
    gemm64(wh1, wl1, xh, xl, bv, lm, l4, pp, f);

    float psum = 0.f, psq = 0.f;
#pragma unroll
    for (int mt = 0; mt < 4; ++mt)
#pragma unroll
        for (int r = 0; r < 4; ++r) { float fv = f[mt][r]; psum += fv; psq += fv * fv; }
    psum += __shfl_xor(psum, 16); psum += __shfl_xor(psum, 32);
    psq  += __shfl_xor(psq, 16);  psq  += __shfl_xor(psq, 32);
    const float m = psum * (1.f / 64.f);
    const float rstd = rsqrtf(psq * (1.f / 64.f) - m * m + EPS_LN);

    float sv_[16];
#pragma unroll
    for (int mt = 0; mt < 4; ++mt)
#pragma unroll
        for (int r = 0; r < 4; ++r) {
            const int o = mt * 16 + l4 * 4 + r;
            float y = bv[64 + o] * (f[mt][r] - m) * rstd + bv[128 + o];
            sv_[mt * 4 + r] = y * sigmoid_f(y);
        }
    __syncthreads();
#pragma unroll
    for (int mt = 0; mt < 4; ++mt) {
        uint h0 = pack2(sv_[4 * mt],     sv_[4 * mt + 1]);
        uint h1 = pack2(sv_[4 * mt + 2], sv_[4 * mt + 3]);
        uint l0 = pack2(sv_[4 * mt]     - __uint_as_float((h0 & 0xffffu) << 16),
                        sv_[4 * mt + 1] - __uint_as_float(h0 & 0xffff0000u));
        uint l1 = pack2(sv_[4 * mt + 2] - __uint_as_float((h1 & 0xffffu) << 16),
                        sv_[4 * mt + 3] - __uint_as_float(h1 & 0xffff0000u));
        const int so = pp * 72 + mt * 16 + l4 * 4;
        *(uint2*)&xh[so] = make_uint2(h0, h1);
        *(uint2*)&xl[so] = make_uint2(l0, l1);
    }
    __syncthreads();

    f32x4 z[4];
    gemm64(wh2, wl2, xh, xl, bv + 192, lm, l4, pp, z);

    float sq = 0.f;
#pragma unroll
    for (int mt = 0; mt < 4; ++mt)
#pragma unroll
        for (int r = 0; r < 4; ++r) sq += z[mt][r] * z[mt][r];
    sq += __shfl_xor(sq, 16); sq += __shfl_xor(sq, 32);

    if (pp < 49) {
        const int py = div7s(pp), px = pp - py * 7;
        const int hwi = (ty * 7 + py) * W + tx * 7 + px;
        ushort* dst = &px16[((size_t)b * HW + hwi) * 64];
#pragma unroll
        for (int mt = 0; mt < 4; ++mt)
            *(uint2*)&dst[mt * 16 + l4 * 4] =
                make_uint2(pack2(z[mt][0], z[mt][1]), pack2(z[mt][2], z[mt][3]));
        if (l4 == 0) sqnorm[(size_t)b * HW + hwi] = sq;
    }
}

// ---------------------------------------------------------------------------
// k23 (r10): P2 MFMA (r7) + P3 NOW MFMA. Fixup conv1 split into comb-part
// (K=64 zero-padded) + sem-part (K=64), accumulating in registers; conv2 as
// a third gemm. LN/gate in the MFMA lane domain (shfl over l4-groups); inv
// crosses to the pixel=lane domain via a 64-entry pt. X/A strips are
// time-multiplexed over the dead dmat region; arena 72192 B -> 2 blocks/CU.
// ---------------------------------------------------------------------------
__global__ __launch_bounds__(256, 2) void k23_fused(
    const ushort* __restrict__ px16, const float* __restrict__ sqnorm,
    const float* __restrict__ sem,  const float* __restrict__ spat,
    const float* __restrict__ fw1, const float* __restrict__ fb1,
    const float* __restrict__ fg,  const float* __restrict__ fbe,
    const float* __restrict__ fw2, const float* __restrict__ fb2,
    const float* __restrict__ w1, const float* __restrict__ b1,
    const float* __restrict__ g,  const float* __restrict__ be,
    const float* __restrict__ w2, const float* __restrict__ b2,
    const float* __restrict__ sigma_, float* __restrict__ out)
{
    __shared__ __align__(16) float smem[18048];          // 72192 B arena
    // P1/P2:
    ushort* haloA = (ushort*)smem;                       // [169][64] bf16 fl [0,5408)
    float*  dmat  = smem + 5408;                         // [176][66] f32 fl [5408,17024)
    float*  sqn_l = smem + 17088;                        // 169 fl [17088,17257)
    // post-extraction (dmat/haloA/sqn dead):
    float*  comb  = smem;                                // 3136 fl [0,3136)
    float*  bv3   = smem + 3136;                         // 256: fb1|fb2|fg|fbe
    float*  pt    = smem + 3136;                         // 64 (overlays dead fb1)
    ushort* Xh    = (ushort*)(smem + 3392);              // [64][72] fl [3392,5696)
    ushort* Xl    = (ushort*)(smem + 5696);              // fl [5696,8000)
    ushort* Ah    = (ushort*)(smem + 8000);              // fl [8000,10304)
    ushort* Al    = (ushort*)(smem + 10304);             // fl [10304,12608)
    ushort* haloB = (ushort*)(smem + 12640);             // [169][64] fl [12640,18048)
    // P5/P6 overlays:
    float*  bvP   = smem + 3136;                         // 256 (pt/bv3 dead)
    ushort* whiP  = (ushort*)(smem + 8000);              // over A strip
    ushort* wloP  = (ushort*)(smem + 10304);
    ushort* ahiP  = (ushort*)(smem + 3392);              // over X strip
    ushort* aloP  = (ushort*)(smem + 5696);

    const int tid = threadIdx.x, lane = tid & 63, wv = tid >> 6;
    const int lm = lane & 15, l4 = lane >> 4;
    int b, ty, tx; decode_blk(blockIdx.x, b, ty, tx);
    const int lp  = lane < 49 ? lane : 48;
    const int py  = div7s(lp), pxl = lp - py * 7;
    const int h = ty * 7 + py, w = tx * 7 + pxl;
    const int hw = h * W + w;
    const int h0 = ty * 7 - 3, w0 = tx * 7 - 3;
    const bool act = lane < 49;
    const int pp = wv * 16 + lm;

    // ---- sv prefetch (P3 input; lives until X2 staging) ----
    float sv[64];
#pragma unroll
    for (int k = 0; k < 64; ++k) sv[k] = sem[(size_t)(b * 64 + k) * HW + hw];

    // ---- P1: stage px halo -> haloA (bf16): 1352 16-B loads ----
    for (int i = 0; i < 6; ++i) {
        int idx = i * 256 + tid;
        if (idx < 1352) {
            int r = idx >> 3, q = idx & 7;
            int ry = div13s(r), rx = r - ry * 13;
            int hh = h0 + ry, ww = w0 + rx;
            bool valid = (unsigned)hh < (unsigned)H && (unsigned)ww < (unsigned)W;
            uint4 v = make_uint4(0u, 0u, 0u, 0u);
            if (valid) v = *(const uint4*)&px16[((size_t)b * HW + hh * W + ww) * 64 + 8 * q];
            *(uint4*)&haloA[(r << 6) + ((q ^ (r & 7)) << 3)] = v;
        }
    }
    if (tid < 169) {
        int ry = div13s(tid), rx = tid - ry * 13;
        int hh = h0 + ry, ww = w0 + rx;
        bool valid = (unsigned)hh < (unsigned)H && (unsigned)ww < (unsigned)W;
        float v = 0.f;
        if (valid) v = sqnorm[(size_t)b * HW + hh * W + ww];
        sqn_l[tid] = v;
    }
    __syncthreads();

    // ---- P2-MFMA: D[hp][p] = <haloA[hp], haloA[rp(p)]> -> dmat f32 ----
    {
        const int qp = pp < 49 ? pp : 48;
        const int pyp = div7s(qp), pxp = qp - pyp * 7;
        const int rpp = pyp * 13 + pxp + 42;
        bf16x8 bc0 = *(const bf16x8*)&haloA[(rpp << 6) + ((l4 ^ (rpp & 7)) << 3)];
        bf16x8 bc1 = *(const bf16x8*)&haloA[(rpp << 6) + (((4 + l4) ^ (rpp & 7)) << 3)];
#pragma unroll
        for (int mt = 0; mt < 11; ++mt) {
            const int r = mt * 16 + lm;
            bf16x8 a0 = *(const bf16x8*)&haloA[(r << 6) + ((l4 ^ (r & 7)) << 3)];
            bf16x8 a1 = *(const bf16x8*)&haloA[(r << 6) + (((4 + l4) ^ (r & 7)) << 3)];
            f32x4 d = {0.f, 0.f, 0.f, 0.f};
            d = mfma16(a0, bc0, d);
            d = mfma16(a1, bc1, d);
            const int orow = mt * 16 + l4 * 4;
#pragma unroll
            for (int rr = 0; rr < 4; ++rr)
                dmat[(orow + rr) * 66 + pp] = d[rr];
        }
    }
    __syncthreads();

    // ---- extraction (wave-split n) into regs ----
    const int rbase = py * 13 + pxl;
    const int rp = rbase + 42;
    float cbl[13];
    {
        const float sqc = sqn_l[rp];
        const float sg_ = sigma_[0];
        const float inv2s2 = rcp_fast(2.f * sg_ * sg_);
#pragma unroll
        for (int i = 0; i < 13; ++i) {
            const int n = uni(wv + 4 * i);
            cbl[i] = 0.f;
            if (n < 49) {
                int ryn = div7s(n), rxn = n - ryn * 7;
                int dy = ryn - 3, dx = rxn - 3;
                int rn = rbase + ryn * 13 + rxn;
                float dot = dmat[rn * 66 + lane];
                float dist2 = fmaxf(sqn_l[rn] + sqc - 2.f * dot, 0.f);
                bool validn = (unsigned)(h + dy) < (unsigned)H && (unsigned)(w + dx) < (unsigned)W;
                float d2n = (float)(dy * dy + dx * dx);
                cbl[i] = validn ? __expf(-(dist2 * (1.f / 128.f) + d2n * inv2s2)) : 0.f;
            }
        }
    }
    __syncthreads();   // dmat/haloA/sqn dead below

    // ---- post-extraction staging: comb f32 + X1(comb bf16) + haloB + A1 + bv3 ----
#pragma unroll
    for (int i = 0; i < 13; ++i) {
        const int n = wv + 4 * i;
        if (n < 49) {
            float v = cbl[i];
            comb[n * 64 + lane] = v;
            ushort hh = rne16(v);
            Xh[lane * 72 + n] = hh;
            Xl[lane * 72 + n] = rne16(v - up1(hh));
        }
    }
    if (tid < 64) {
#pragma unroll
        for (int r = 49; r < 64; ++r) { Xh[tid * 72 + r] = 0; Xl[tid * 72 + r] = 0; }
        bv3[tid]       = (tid < 49) ? fb1[tid] : 0.f;
        bv3[64 + tid]  = (tid < 49) ? fb2[tid] : 0.f;
        bv3[128 + tid] = (tid < 49) ? fg[tid]  : 0.f;
        bv3[192 + tid] = (tid < 49) ? fbe[tid] : 0.f;
    }
    if (tid < 169) {
        const int ry = div13s(tid), rx = tid - ry * 13;
        const int hh = h0 + ry, ww = w0 + rx;
        const bool valid = (unsigned)hh < (unsigned)H && (unsigned)ww < (unsigned)W;
        const int soff = hh * W + ww;
        const int rsw = (tid & 7), rb_ = tid << 6;
#pragma unroll
        for (int cq = 0; cq < 8; ++cq) {
            uint4 v = make_uint4(0u, 0u, 0u, 0u);
            if (valid) {
                const float* sp = &spat[(size_t)(b * 64 + 8 * cq) * HW + soff];
                v.x = pack2(sp[0],      sp[HW]);
                v.y = pack2(sp[2 * HW], sp[3 * HW]);
                v.z = pack2(sp[4 * HW], sp[5 * HW]);
                v.w = pack2(sp[6 * HW], sp[7 * HW]);
            }
            *(uint4*)&haloB[rb_ + ((cq ^ rsw) << 3)] = v;
        }
    }
    stage_wpad(fw1, 113, 49, 49, Ah, Al, tid);   // A1 = comb-half of fx_w1
    __syncthreads();

    // ---- P3-MFMA: conv1 = A1*X1 + A2*X2, conv2 = A3*X3 ----
    f32x4 accF[4];
    gemm64(Ah, Al, Xh, Xl, bv3, lm, l4, pp, accF);   // bias fb1 + comb part
    __syncthreads();                                  // A1/X1 reads done

    // X2 = sem (from sv), A2 = sem-half of fx_w1
    {
        uint hu[8], lu[8];
#pragma unroll
        for (int jj = 0; jj < 8; ++jj) {
            float x0 = sv[wv * 16 + 2 * jj], x1 = sv[wv * 16 + 2 * jj + 1];
            uint hh = pack2(x0, x1);
            hu[jj] = hh;
            lu[jj] = pack2(x0 - __uint_as_float((hh & 0xffffu) << 16),
                           x1 - __uint_as_float(hh & 0xffff0000u));
        }
        const int rb = lane * 72 + wv * 16;
        *(uint4*)&Xh[rb]     = make_uint4(hu[0], hu[1], hu[2], hu[3]);
        *(uint4*)&Xh[rb + 8] = make_uint4(hu[4], hu[5], hu[6], hu[7]);
        *(uint4*)&Xl[rb]     = make_uint4(lu[0], lu[1], lu[2], lu[3]);
        *(uint4*)&Xl[rb + 8] = make_uint4(lu[4], lu[5], lu[6], lu[7]);
    }
    stage_wpad(fw1 + 49, 113, 49, 64, Ah, Al, tid);
    __syncthreads();

    gemm64_acc(Ah, Al, Xh, Xl, lm, l4, pp, accF);    // += sem part

    // LN over o<49 (shfl across l4-groups) + SiLU -> s in regs
    float sarr[16];
    {
        float psum = 0.f, psq = 0.f;
#pragma unroll
        for (int mt = 0; mt < 4; ++mt)
#pragma unroll
            for (int r = 0; r < 4; ++r) {
                const int o = mt * 16 + l4 * 4 + r;
                if (o < 49) { float fv = accF[mt][r]; psum += fv; psq += fv * fv; }
            }
        psum += __shfl_xor(psum, 16); psum += __shfl_xor(psum, 32);
        psq  += __shfl_xor(psq, 16);  psq  += __shfl_xor(psq, 32);
        const float m = psum * (1.f / 49.f);
        const float rstd = rsqrtf(psq * (1.f / 49.f) - m * m + EPS_LN);
#pragma unroll
        for (int mt = 0; mt < 4; ++mt)
#pragma unroll
            for (int r = 0; r < 4; ++r) {
                const int o = mt * 16 + l4 * 4 + r;
                float s = 0.f;
                if (o < 49) {
                    float y = bv3[128 + o] * (accF[mt][r] - m) * rstd + bv3[192 + o];
                    s = y * sigmoid_f(y);
                }
                sarr[mt * 4 + r] = s;
            }
    }
    __syncthreads();                                  // A2/X2 reads done

    // X3 = s (rows o, col pp), A3 = fx_w2
#pragma unroll
    for (int mt = 0; mt < 4; ++mt) {
        uint h0_ = pack2(sarr[4 * mt],     sarr[4 * mt + 1]);
        uint h1_ = pack2(sarr[4 * mt + 2], sarr[4 * mt + 3]);
        uint l0_ = pack2(sarr[4 * mt]     - __uint_as_float((h0_ & 0xffffu) << 16),
                         sarr[4 * mt + 1] - __uint_as_float(h0_ & 0xffff0000u));
        uint l1_ = pack2(sarr[4 * mt + 2] - __uint_as_float((h1_ & 0xffffu) << 16),
                         sarr[4 * mt + 3] - __uint_as_float(h1_ & 0xffff0000u));
        const int so = pp * 72 + mt * 16 + l4 * 4;
        *(uint2*)&Xh[so] = make_uint2(h0_, h1_);
        *(uint2*)&Xl[so] = make_uint2(l0_, l1_);
    }
    stage_wpad(fw2, 49, 49, 49, Ah, Al, tid);
    __syncthreads();

    f32x4 accG[4];
    gemm64(Ah, Al, Xh, Xl, bv3 + 64, lm, l4, pp, accG);   // bias fb2

    // gate + comb update + column sums -> pt[pp]
    {
        float tacc = 0.f;
#pragma unroll
        for (int mt = 0; mt < 4; ++mt)
#pragma unroll
            for (int r = 0; r < 4; ++r) {
                const int o = mt * 16 + l4 * 4 + r;
                if (o < 49) {
                    float gate = 1.f + sigmoid_f(accG[mt][r]);
                    float cx = comb[o * 64 + pp] * gate;   // unique (o,pp) per lane
                    comb[o * 64 + pp] = cx;
                    tacc += cx;
                }
            }
        tacc += __shfl_xor(tacc, 16); tacc += __shfl_xor(tacc, 32);
        if (l4 == 0) pt[pp] = tacc;
    }
    __syncthreads();
    const float inv = rcp_fast(pt[lane] + EPS_NORM);
    __syncthreads();   // all pt reads done -> bvP overlay safe

    // ---- stage op_w1 (over dead A strip) + bias vec; hides under P5 ----
    stage_w(w1, whiP, wloP, tid);
    if (tid < 64) { bvP[tid] = b1[tid]; bvP[64 + tid] = g[tid];
                    bvP[128 + tid] = be[tid]; bvP[192 + tid] = b2[tid]; }

    // ---- P5: weighted neighborhood reduction (haloB) ----
    const int c0 = uni(wv * 16);
    const int qq0 = c0 >> 3;
    float acc[16];
#pragma unroll
    for (int j = 0; j < 16; ++j) acc[j] = 0.f;
    for (int n = 0; n < 49; ++n) {
        int ryn = n / 7, rxn = n - ryn * 7;
        int rn = rbase + ryn * 13 + rxn;
        float cn = comb[n * 64 + lane] * inv;
        const int rb_ = rn << 6, rsw = rn & 7;
#pragma unroll
        for (int q = 0; q < 2; ++q) {
            uint4 v = *(const uint4*)&haloB[rb_ + (((qq0 + q) ^ rsw) << 3)];
            float2 a = up2(v.x), bb = up2(v.y), c = up2(v.z), d = up2(v.w);
            acc[8 * q + 0] += cn * a.x;  acc[8 * q + 1] += cn * a.y;
            acc[8 * q + 2] += cn * bb.x; acc[8 * q + 3] += cn * bb.y;
            acc[8 * q + 4] += cn * c.x;  acc[8 * q + 5] += cn * c.y;
            acc[8 * q + 6] += cn * d.x;  acc[8 * q + 7] += cn * d.y;
        }
    }
    __syncthreads();   // comb/haloB reads done; whiP/bvP staging visible

    // ---- P6a: write P5 result as split-bf16 activations [pixel][72] ----
    {
        uint hu[8], lu[8];
#pragma unroll
        for (int jj = 0; jj < 8; ++jj) {
            float x0 = act ? acc[2 * jj] : 0.f;
            float x1 = act ? acc[2 * jj + 1] : 0.f;
            uint hh = pack2(x0, x1);
            hu[jj] = hh;
            lu[jj] = pack2(x0 - __uint_as_float((hh & 0xffffu) << 16),
                           x1 - __uint_as_float(hh & 0xffff0000u));
        }
        const int rb = lane * 72 + c0;
        *(uint4*)&ahiP[rb]     = make_uint4(hu[0], hu[1], hu[2], hu[3]);
        *(uint4*)&ahiP[rb + 8] = make_uint4(hu[4], hu[5], hu[6], hu[7]);
        *(uint4*)&aloP[rb]     = make_uint4(lu[0], lu[1], lu[2], lu[3]);
        *(uint4*)&aloP[rb + 8] = make_uint4(lu[4], lu[5], lu[6], lu[7]);
    }
    __syncthreads();

    // ---- P6b: conv1 MFMA + LN(shfl) ----
    f32x4 f6[4];
    gemm64(whiP, wloP, ahiP, aloP, bvP, lm, l4, pp, f6);

    float psum = 0.f, psq = 0.f;
#pragma unroll
    for (int mt = 0; mt < 4; ++mt)
#pragma unroll
        for (int r = 0; r < 4; ++r) { float fv = f6[mt][r]; psum += fv; psq += fv * fv; }
    psum += __shfl_xor(psum, 16); psum += __shfl_xor(psum, 32);
    psq  += __shfl_xor(psq, 16);  psq  += __shfl_xor(psq, 32);
    const float m6 = psum * (1.f / 64.f);
    const float rstd6 = rsqrtf(psq * (1.f / 64.f) - m6 * m6 + EPS_LN);

    float yv[16];
#pragma unroll
    for (int mt = 0; mt < 4; ++mt)
#pragma unroll
        for (int r = 0; r < 4; ++r) {
            const int o = mt * 16 + l4 * 4 + r;
            yv[mt * 4 + r] = bvP[64 + o] * (f6[mt][r] - m6) * rstd6 + bvP[128 + o];
        }
    __syncthreads();   // conv1 fragment reads done -> strips reusable

    // write y (split bf16) over act strip; restage op_w2 over W strip
#pragma unroll
    for (int mt = 0; mt < 4; ++mt) {
        uint h0_ = pack2(yv[4 * mt],     yv[4 * mt + 1]);
        uint h1_ = pack2(yv[4 * mt + 2], yv[4 * mt + 3]);
        uint l0_ = pack2(yv[4 * mt]     - __uint_as_float((h0_ & 0xffffu) << 16),
                         yv[4 * mt + 1] - __uint_as_float(h0_ & 0xffff0000u));
        uint l1_ = pack2(yv[4 * mt + 2] - __uint_as_float((h1_ & 0xffffu) << 16),
                         yv[4 * mt + 3] - __uint_as_float(h1_ & 0xffff0000u));
        const int so = pp * 72 + mt * 16 + l4 * 4;
        *(uint2*)&ahiP[so] = make_uint2(h0_, h1_);
        *(uint2*)&aloP[so] = make_uint2(l0_, l1_);
    }
    stage_w(w2, whiP, wloP, tid);
    __syncthreads();

    // ---- P6c: conv2 MFMA + store ----
    f32x4 z6[4];
    gemm64(whiP, wloP, ahiP, aloP, bvP + 192, lm, l4, pp, z6);

    if (pp < 49) {
        const int py6 = div7s(pp), px6 = pp - py6 * 7;
        const int hwi6 = (ty * 7 + py6) * W + tx * 7 + px6;
#pragma unroll
        for (int mt = 0; mt < 4; ++mt)
#pragma unroll
            for (int r = 0; r < 4; ++r)
                out[(size_t)(b * 64 + mt * 16 + l4 * 4 + r) * HW + hwi6] = z6[mt][r];
    }
}

extern "C" void kernel_launch(void* const* d_in, const int* in_sizes, int n_in,
                              void* d_out, int out_size, void* d_ws, size_t ws_size,
                              hipStream_t stream)
{
    const float* spatial  = (const float*)d_in[0];
    const float* semantic = (const float*)d_in[1];
    const float* rp_w1 = (const float*)d_in[2];
    const float* rp_b1 = (const float*)d_in[3];
    const float* rp_g  = (const float*)d_in[4];
    const float* rp_be = (const float*)d_in[5];
    const float* rp_w2 = (const float*)d_in[6];
    const float* rp_b2 = (const float*)d_in[7];
    const float* fx_w1 = (const float*)d_in[8];
    const float* fx_b1 = (const float*)d_in[9];
    const float* fx_g  = (const float*)d_in[10];
    const float* fx_be = (const float*)d_in[11];
    const float* fx_w2 = (const float*)d_in[12];
    const float* fx_b2 = (const float*)d_in[13];
    const float* op_w1 = (const float*)d_in[14];
    const float* op_b1 = (const float*)d_in[15];
    const float* op_g  = (const float*)d_in[16];
    const float* op_be = (const float*)d_in[17];
    const float* op_w2 = (const float*)d_in[18];
    const float* op_b2 = (const float*)d_in[19];
    const float* sigma = (const float*)d_in[20];

    ushort* px16  = (ushort*)d_ws;                              // 3.21 MB
    float* sqnorm = (float*)((char*)d_ws + (size_t)NPIX * 64 * 2);

    k1_range_proj<<<NBLK, 256, 0, stream>>>(
        semantic, rp_w1, rp_b1, rp_g, rp_be, rp_w2, rp_b2, px16, sqnorm);
    k23_fused<<<NBLK, 256, 0, stream>>>(
        px16, sqnorm, semantic, spatial,
        fx_w1, fx_b1, fx_g, fx_be, fx_w2, fx_b2,
        op_w1, op_b1, op_g, op_be, op_w2, op_b2,
        sigma, (float*)d_out);
}

// Round 11
// 142.651 us; speedup vs baseline: 1.2355x; 1.0669x over previous
//
#include <hip/hip_runtime.h>

typedef unsigned short ushort;
typedef unsigned int uint;

constexpr int B = 2, C = 64, H = 112, W = 112;
constexpr int HW = H * W;          // 12544
constexpr int NPIX = B * HW;       // 25088
constexpr int NBLK = 512;          // 2 images x 16x16 tiles of 7x7 -> exactly 2 blocks/CU
constexpr float EPS_LN = 1e-6f, EPS_NORM = 1e-7f;

typedef __attribute__((ext_vector_type(8))) short bf16x8;   // 8 bf16 = 4 VGPRs
typedef __attribute__((ext_vector_type(4))) float f32x4;

__device__ __forceinline__ float rcp_fast(float x) { return __builtin_amdgcn_rcpf(x); }
__device__ __forceinline__ float sigmoid_f(float x) { return rcp_fast(1.f + __expf(-x)); }
__device__ __forceinline__ int uni(int x) { return __builtin_amdgcn_readfirstlane(x); }
__device__ __forceinline__ int div7s(int x)  { return (x * 9363) >> 16; }   // exact for 0<=x<64
__device__ __forceinline__ int div13s(int x) { return (x * 5042) >> 16; }   // exact for 0<=x<169

// f32 -> bf16 bits (round-nearest-even) + pair pack/unpack.
__device__ __forceinline__ ushort rne16(float x) {
    uint u = __float_as_uint(x);
    u += 0x7fffu + ((u >> 16) & 1u);
    return (ushort)(u >> 16);
}
__device__ __forceinline__ uint pack2(float a, float b) {
    return (uint)rne16(a) | ((uint)rne16(b) << 16);
}
__device__ __forceinline__ float2 up2(uint u) {
    return make_float2(__uint_as_float(u << 16), __uint_as_float(u & 0xffff0000u));
}
__device__ __forceinline__ float up1(ushort u) {
    return __uint_as_float((uint)u << 16);
}

__device__ __forceinline__ f32x4 mfma16(bf16x8 a, bf16x8 b, f32x4 c) {
    return __builtin_amdgcn_mfma_f32_16x16x32_bf16(a, b, c, 0, 0, 0);
}

// XCD-patch swizzle (BOTH kernels -> producer/consumer share an XCD L2).
__device__ __forceinline__ void decode_blk(int blk, int& b, int& ty, int& tx) {
    int p8 = blk & 7, i = blk >> 3;          // i in [0,64)
    b = p8 >> 2;
    int quad = p8 & 3;
    int lty = i >> 3, ltx = i & 7;           // 8x8 tiles per quadrant
    ty = (quad >> 1) * 8 + lty;              // [0,16)
    tx = (quad & 1) * 8 + ltx;
}

// ---------------------------------------------------------------------------
// Split-bf16 GEMM helpers. Weights/activations [64 rows][72] bf16 hi/lo.
// ---------------------------------------------------------------------------
__device__ __forceinline__ void stage_w(const float* __restrict__ wsrc,
                                        ushort* wh, ushort* wl, int tid)
{
#pragma unroll
    for (int i = 0; i < 8; ++i) {
        int idx2 = i * 256 + tid;            // 2048 float pairs = 64x64
        int o = idx2 >> 5, k = (idx2 & 31) * 2;
        float2 xy = *(const float2*)&wsrc[o * 64 + k];
        uint h = pack2(xy.x, xy.y);
        *(uint*)&wh[o * 72 + k] = h;
        *(uint*)&wl[o * 72 + k] = pack2(xy.x - __uint_as_float((h & 0xffffu) << 16),
                                        xy.y - __uint_as_float(h & 0xffff0000u));
    }
}

// Stage a nrow x ncol (<=64x64) matrix with arbitrary row stride into the
// zero-padded [64][72] hi/lo strips. thread t: row t>>2, col quarter t&3.
__device__ __forceinline__ void stage_wpad(const float* __restrict__ src, int ld,
                                           int nrow, int ncol,
                                           ushort* wh, ushort* wl, int tid)
{
    const int o = tid >> 2, q = (tid & 3) * 16;
#pragma unroll
    for (int jj = 0; jj < 8; ++jj) {
        int c = q + 2 * jj;
        float x0 = (o < nrow && c < ncol)     ? src[o * ld + c]     : 0.f;
        float x1 = (o < nrow && c + 1 < ncol) ? src[o * ld + c + 1] : 0.f;
        uint hh = pack2(x0, x1);
        uint ll = pack2(x0 - __uint_as_float((hh & 0xffffu) << 16),
                        x1 - __uint_as_float(hh & 0xffff0000u));
        *(uint*)&wh[o * 72 + c] = hh;
        *(uint*)&wl[o * 72 + c] = ll;
    }
}

__device__ __forceinline__ void gemm64_acc(const ushort* __restrict__ wh, const ushort* __restrict__ wl,
                                           const ushort* __restrict__ xh, const ushort* __restrict__ xl,
                                           int lm, int l4, int pp, f32x4 acc[4])
{
#pragma unroll
    for (int kt = 0; kt < 2; ++kt) {
        const int xo = pp * 72 + kt * 32 + l4 * 8;
        bf16x8 bh = *(const bf16x8*)&xh[xo];
        bf16x8 bl = *(const bf16x8*)&xl[xo];
#pragma unroll
        for (int mt = 0; mt < 4; ++mt) {
            const int wo = (mt * 16 + lm) * 72 + kt * 32 + l4 * 8;
            bf16x8 ah = *(const bf16x8*)&wh[wo];
            bf16x8 al = *(const bf16x8*)&wl[wo];
            acc[mt] = mfma16(al, bh, acc[mt]);
            acc[mt] = mfma16(ah, bl, acc[mt]);
            acc[mt] = mfma16(ah, bh, acc[mt]);
        }
    }
}

__device__ __forceinline__ void gemm64(const ushort* __restrict__ wh, const ushort* __restrict__ wl,
                                       const ushort* __restrict__ xh, const ushort* __restrict__ xl,
                                       const float* __restrict__ bias,
                                       int lm, int l4, int pp, f32x4 acc[4])
{
#pragma unroll
    for (int mt = 0; mt < 4; ++mt) {
        const int ob = mt * 16 + l4 * 4;
        acc[mt][0] = bias[ob]; acc[mt][1] = bias[ob + 1];
        acc[mt][2] = bias[ob + 2]; acc[mt][3] = bias[ob + 3];
    }
    gemm64_acc(wh, wl, xh, xl, lm, l4, pp, acc);
}

// ---------------------------------------------------------------------------
// k1: px = range_proj(semantic) -> px16[p][64] (bf16) + sqnorm[p].
// Unchanged from r7 (full split-bf16 MFMA; verified; ~7 us).
// ---------------------------------------------------------------------------
__global__ __launch_bounds__(256) void k1_range_proj(
    const float* __restrict__ sem,
    const float* __restrict__ w1, const float* __restrict__ b1,
    const float* __restrict__ g,  const float* __restrict__ be,
    const float* __restrict__ w2, const float* __restrict__ b2,
    ushort* __restrict__ px16, float* __restrict__ sqnorm)
{
    __shared__ __align__(16) ushort u16[28160];   // 56320 B
    ushort* wh1 = u16;                 // [64][72] each (4608 ushorts)
    ushort* wl1 = u16 + 4608;
    ushort* wh2 = u16 + 9216;
    ushort* wl2 = u16 + 13824;
    ushort* xh  = u16 + 18432;         // activations / s (reused)
    ushort* xl  = u16 + 23040;         // ..27648
    float*  bv  = (float*)(u16 + 27648);   // b1|g|be|b2 (256 floats)

    const int tid = threadIdx.x, lane = tid & 63, wv = tid >> 6;
    const int lm = lane & 15, l4 = lane >> 4;
    int b, ty, tx; decode_blk(blockIdx.x, b, ty, tx);

    {
        const int lp = lane < 49 ? lane : 48;
        const int py = div7s(lp), px = lp - py * 7;
        const int hw = (ty * 7 + py) * W + tx * 7 + px;
        const bool a = lane < 49;
        float xv[16];
#pragma unroll
        for (int j = 0; j < 16; ++j)
            xv[j] = a ? sem[(size_t)(b * 64 + wv * 16 + j) * HW + hw] : 0.f;
        uint hu[8], lu[8];
#pragma unroll
        for (int jj = 0; jj < 8; ++jj) {
            uint hh = pack2(xv[2 * jj], xv[2 * jj + 1]);
            hu[jj] = hh;
            lu[jj] = pack2(xv[2 * jj]     - __uint_as_float((hh & 0xffffu) << 16),
                           xv[2 * jj + 1] - __uint_as_float(hh & 0xffff0000u));
        }
        const int rb = lane * 72 + wv * 16;
        *(uint4*)&xh[rb]     = make_uint4(hu[0], hu[1], hu[2], hu[3]);
        *(uint4*)&xh[rb + 8] = make_uint4(hu[4], hu[5], hu[6], hu[7]);
        *(uint4*)&xl[rb]     = make_uint4(lu[0], lu[1], lu[2], lu[3]);
        *(uint4*)&xl[rb + 8] = make_uint4(lu[4], lu[5], lu[6], lu[7]);
    }
    stage_w(w1, wh1, wl1, tid);
    stage_w(w2, wh2, wl2, tid);
    if (tid < 64) { bv[tid] = b1[tid]; bv[64 + tid] = g[tid];
                    bv[128 + tid] = be[tid]; bv[192 + tid] = b2[tid]; }
    __syncthreads();

    const int pp = wv * 16 + lm;
    f32x4 f[4];
    gemm64(wh1, wl1, xh, xl, bv, lm, l4, pp, f);

    float psum = 0.f, psq = 0.f;
#pragma unroll
    for (int mt = 0; mt < 4; ++mt)
#pragma unroll
        for (int r = 0; r < 4; ++r) { float fv = f[mt][r]; psum += fv; psq += fv * fv; }
    psum += __shfl_xor(psum, 16); psum += __shfl_xor(psum, 32);
    psq  += __shfl_xor(psq, 16);  psq  += __shfl_xor(psq, 32);
    const float m = psum * (1.f / 64.f);
    const float rstd = rsqrtf(psq * (1.f / 64.f) - m * m + EPS_LN);

    float sv_[16];
#pragma unroll
    for (int mt = 0; mt < 4; ++mt)
#pragma unroll
        for (int r = 0; r < 4; ++r) {
            const int o = mt * 16 + l4 * 4 + r;
            float y = bv[64 + o] * (f[mt][r] - m) * rstd + bv[128 + o];
            sv_[mt * 4 + r] = y * sigmoid_f(y);
        }
    __syncthreads();
#pragma unroll
    for (int mt = 0; mt < 4; ++mt) {
        uint h0 = pack2(sv_[4 * mt],     sv_[4 * mt + 1]);
        uint h1 = pack2(sv_[4 * mt + 2], sv_[4 * mt + 3]);
        uint l0 = pack2(sv_[4 * mt]     - __uint_as_float((h0 & 0xffffu) << 16),
                        sv_[4 * mt + 1] - __uint_as_float(h0 & 0xffff0000u));
        uint l1 = pack2(sv_[4 * mt + 2] - __uint_as_float((h1 & 0xffffu) << 16),
                        sv_[4 * mt + 3] - __uint_as_float(h1 & 0xffff0000u));
        const int so = pp * 72 + mt * 16 + l4 * 4;
        *(uint2*)&xh[so] = make_uint2(h0, h1);
        *(uint2*)&xl[so] = make_uint2(l0, l1);
    }
    __syncthreads();

    f32x4 z[4];
    gemm64(wh2, wl2, xh, xl, bv + 192, lm, l4, pp, z);

    float sq = 0.f;
#pragma unroll
    for (int mt = 0; mt < 4; ++mt)
#pragma unroll
        for (int r = 0; r < 4; ++r) sq += z[mt][r] * z[mt][r];
    sq += __shfl_xor(sq, 16); sq += __shfl_xor(sq, 32);

    if (pp < 49) {
        const int py = div7s(pp), px = pp - py * 7;
        const int hwi = (ty * 7 + py) * W + tx * 7 + px;
        ushort* dst = &px16[((size_t)b * HW + hwi) * 64];
#pragma unroll
        for (int mt = 0; mt < 4; ++mt)
            *(uint2*)&dst[mt * 16 + l4 * 4] =
                make_uint2(pack2(z[mt][0], z[mt][1]), pack2(z[mt][2], z[mt][3]));
        if (l4 == 0) sqnorm[(size_t)b * HW + hwi] = sq;
    }
}

// ---------------------------------------------------------------------------
// k23 (r11): identical to r10 except sv[64] -> sv16[16]. r10's P3-MFMA only
// consumes channels [wv*16, wv*16+16) per thread at X2 staging; the old
// 64-wide prefetch cost 48 extra VGPRs of long-range live state -> ~60
// f32/thread scratch spill (WRITE_SIZE 6.3->39 MB). 16-wide kills the spill
// and cuts the sem re-read 4x. Arithmetic bit-identical to r10.
// ---------------------------------------------------------------------------
__global__ __launch_bounds__(256, 2) void k23_fused(
    const ushort* __restrict__ px16, const float* __restrict__ sqnorm,
    const float* __restrict__ sem,  const float* __restrict__ spat,
    const float* __restrict__ fw1, const float* __restrict__ fb1,
    const float* __restrict__ fg,  const float* __restrict__ fbe,
    const float* __restrict__ fw2, const float* __restrict__ fb2,
    const float* __restrict__ w1, const float* __restrict__ b1,
    const float* __restrict__ g,  const float* __restrict__ be,
    const float* __restrict__ w2, const float* __restrict__ b2,
    const float* __restrict__ sigma_, float* __restrict__ out)
{
    __shared__ __align__(16) float smem[18048];          // 72192 B arena
    // P1/P2:
    ushort* haloA = (ushort*)smem;                       // [169][64] bf16 fl [0,5408)
    float*  dmat  = smem + 5408;                         // [176][66] f32 fl [5408,17024)
    float*  sqn_l = smem + 17088;                        // 169 fl [17088,17257)
    // post-extraction (dmat/haloA/sqn dead):
    float*  comb  = smem;                                // 3136 fl [0,3136)
    float*  bv3   = smem + 3136;                         // 256: fb1|fb2|fg|fbe
    float*  pt    = smem + 3136;                         // 64 (overlays dead fb1)
    ushort* Xh    = (ushort*)(smem + 3392);              // [64][72] fl [3392,5696)
    ushort* Xl    = (ushort*)(smem + 5696);              // fl [5696,8000)
    ushort* Ah    = (ushort*)(smem + 8000);              // fl [8000,10304)
    ushort* Al    = (ushort*)(smem + 10304);             // fl [10304,12608)
    ushort* haloB = (ushort*)(smem + 12640);             // [169][64] fl [12640,18048)
    // P5/P6 overlays:
    float*  bvP   = smem + 3136;                         // 256 (pt/bv3 dead)
    ushort* whiP  = (ushort*)(smem + 8000);              // over A strip
    ushort* wloP  = (ushort*)(smem + 10304);
    ushort* ahiP  = (ushort*)(smem + 3392);              // over X strip
    ushort* aloP  = (ushort*)(smem + 5696);

    const int tid = threadIdx.x, lane = tid & 63, wv = tid >> 6;
    const int lm = lane & 15, l4 = lane >> 4;
    int b, ty, tx; decode_blk(blockIdx.x, b, ty, tx);
    const int lp  = lane < 49 ? lane : 48;
    const int py  = div7s(lp), pxl = lp - py * 7;
    const int h = ty * 7 + py, w = tx * 7 + pxl;
    const int hw = h * W + w;
    const int h0 = ty * 7 - 3, w0 = tx * 7 - 3;
    const bool act = lane < 49;
    const int pp = wv * 16 + lm;

    // ---- sv16 prefetch: ONLY this thread's 16-channel slice (X2 staging) ----
    float sv16[16];
#pragma unroll
    for (int j = 0; j < 16; ++j)
        sv16[j] = sem[(size_t)(b * 64 + wv * 16 + j) * HW + hw];

    // ---- P1: stage px halo -> haloA (bf16): 1352 16-B loads ----
    for (int i = 0; i < 6; ++i) {
        int idx = i * 256 + tid;
        if (idx < 1352) {
            int r = idx >> 3, q = idx & 7;
            int ry = div13s(r), rx = r - ry * 13;
            int hh = h0 + ry, ww = w0 + rx;
            bool valid = (unsigned)hh < (unsigned)H && (unsigned)ww < (unsigned)W;
            uint4 v = make_uint4(0u, 0u, 0u, 0u);
            if (valid) v = *(const uint4*)&px16[((size_t)b * HW + hh * W + ww) * 64 + 8 * q];
            *(uint4*)&haloA[(r << 6) + ((q ^ (r & 7)) << 3)] = v;
        }
    }
    if (tid < 169) {
        int ry = div13s(tid), rx = tid - ry * 13;
        int hh = h0 + ry, ww = w0 + rx;
        bool valid = (unsigned)hh < (unsigned)H && (unsigned)ww < (unsigned)W;
        float v = 0.f;
        if (valid) v = sqnorm[(size_t)b * HW + hh * W + ww];
        sqn_l[tid] = v;
    }
    __syncthreads();

    // ---- P2-MFMA: D[hp][p] = <haloA[hp], haloA[rp(p)]> -> dmat f32 ----
    {
        const int qp = pp < 49 ? pp : 48;
        const int pyp = div7s(qp), pxp = qp - pyp * 7;
        const int rpp = pyp * 13 + pxp + 42;
        bf16x8 bc0 = *(const bf16x8*)&haloA[(rpp << 6) + ((l4 ^ (rpp & 7)) << 3)];
        bf16x8 bc1 = *(const bf16x8*)&haloA[(rpp << 6) + (((4 + l4) ^ (rpp & 7)) << 3)];
#pragma unroll
        for (int mt = 0; mt < 11; ++mt) {
            const int r = mt * 16 + lm;
            bf16x8 a0 = *(const bf16x8*)&haloA[(r << 6) + ((l4 ^ (r & 7)) << 3)];
            bf16x8 a1 = *(const bf16x8*)&haloA[(r << 6) + (((4 + l4) ^ (r & 7)) << 3)];
            f32x4 d = {0.f, 0.f, 0.f, 0.f};
            d = mfma16(a0, bc0, d);
            d = mfma16(a1, bc1, d);
            const int orow = mt * 16 + l4 * 4;
#pragma unroll
            for (int rr = 0; rr < 4; ++rr)
                dmat[(orow + rr) * 66 + pp] = d[rr];
        }
    }
    __syncthreads();

    // ---- extraction (wave-split n) into regs ----
    const int rbase = py * 13 + pxl;
    const int rp = rbase + 42;
    float cbl[13];
    {
        const float sqc = sqn_l[rp];
        const float sg_ = sigma_[0];
        const float inv2s2 = rcp_fast(2.f * sg_ * sg_);
#pragma unroll
        for (int i = 0; i < 13; ++i) {
            const int n = uni(wv + 4 * i);
            cbl[i] = 0.f;
            if (n < 49) {
                int ryn = div7s(n), rxn = n - ryn * 7;
                int dy = ryn - 3, dx = rxn - 3;
                int rn = rbase + ryn * 13 + rxn;
                float dot = dmat[rn * 66 + lane];
                float dist2 = fmaxf(sqn_l[rn] + sqc - 2.f * dot, 0.f);
                bool validn = (unsigned)(h + dy) < (unsigned)H && (unsigned)(w + dx) < (unsigned)W;
                float d2n = (float)(dy * dy + dx * dx);
                cbl[i] = validn ? __expf(-(dist2 * (1.f / 128.f) + d2n * inv2s2)) : 0.f;
            }
        }
    }
    __syncthreads();   // dmat/haloA/sqn dead below

    // ---- post-extraction staging: comb f32 + X1(comb bf16) + haloB + A1 + bv3 ----
#pragma unroll
    for (int i = 0; i < 13; ++i) {
        const int n = wv + 4 * i;
        if (n < 49) {
            float v = cbl[i];
            comb[n * 64 + lane] = v;
            ushort hh = rne16(v);
            Xh[lane * 72 + n] = hh;
            Xl[lane * 72 + n] = rne16(v - up1(hh));
        }
    }
    if (tid < 64) {
#pragma unroll
        for (int r = 49; r < 64; ++r) { Xh[tid * 72 + r] = 0; Xl[tid * 72 + r] = 0; }
        bv3[tid]       = (tid < 49) ? fb1[tid] : 0.f;
        bv3[64 + tid]  = (tid < 49) ? fb2[tid] : 0.f;
        bv3[128 + tid] = (tid < 49) ? fg[tid]  : 0.f;
        bv3[192 + tid] = (tid < 49) ? fbe[tid] : 0.f;
    }
    if (tid < 169) {
        const int ry = div13s(tid), rx = tid - ry * 13;
        const int hh = h0 + ry, ww = w0 + rx;
        const bool valid = (unsigned)hh < (unsigned)H && (unsigned)ww < (unsigned)W;
        const int soff = hh * W + ww;
        const int rsw = (tid & 7), rb_ = tid << 6;
#pragma unroll
        for (int cq = 0; cq < 8; ++cq) {
            uint4 v = make_uint4(0u, 0u, 0u, 0u);
            if (valid) {
                const float* sp = &spat[(size_t)(b * 64 + 8 * cq) * HW + soff];
                v.x = pack2(sp[0],      sp[HW]);
                v.y = pack2(sp[2 * HW], sp[3 * HW]);
                v.z = pack2(sp[4 * HW], sp[5 * HW]);
                v.w = pack2(sp[6 * HW], sp[7 * HW]);
            }
            *(uint4*)&haloB[rb_ + ((cq ^ rsw) << 3)] = v;
        }
    }
    stage_wpad(fw1, 113, 49, 49, Ah, Al, tid);   // A1 = comb-half of fx_w1
    __syncthreads();

    // ---- P3-MFMA: conv1 = A1*X1 + A2*X2, conv2 = A3*X3 ----
    f32x4 accF[4];
    gemm64(Ah, Al, Xh, Xl, bv3, lm, l4, pp, accF);   // bias fb1 + comb part
    __syncthreads();                                  // A1/X1 reads done

    // X2 = sem (from sv16), A2 = sem-half of fx_w1
    {
        uint hu[8], lu[8];
#pragma unroll
        for (int jj = 0; jj < 8; ++jj) {
            float x0 = sv16[2 * jj], x1 = sv16[2 * jj + 1];
            uint hh = pack2(x0, x1);
            hu[jj] = hh;
            lu[jj] = pack2(x0 - __uint_as_float((hh & 0xffffu) << 16),
                           x1 - __uint_as_float(hh & 0xffff0000u));
        }
        const int rb = lane * 72 + wv * 16;
        *(uint4*)&Xh[rb]     = make_uint4(hu[0], hu[1], hu[2], hu[3]);
        *(uint4*)&Xh[rb + 8] = make_uint4(hu[4], hu[5], hu[6], hu[7]);
        *(uint4*)&Xl[rb]     = make_uint4(lu[0], lu[1], lu[2], lu[3]);
        *(uint4*)&Xl[rb + 8] = make_uint4(lu[4], lu[5], lu[6], lu[7]);
    }
    stage_wpad(fw1 + 49, 113, 49, 64, Ah, Al, tid);
    __syncthreads();

    gemm64_acc(Ah, Al, Xh, Xl, lm, l4, pp, accF);    // += sem part

    // LN over o<49 (shfl across l4-groups) + SiLU -> s in regs
    float sarr[16];
    {
        float psum = 0.f, psq = 0.f;
#pragma unroll
        for (int mt = 0; mt < 4; ++mt)
#pragma unroll
            for (int r = 0; r < 4; ++r) {
                const int o = mt * 16 + l4 * 4 + r;
                if (o < 49) { float fv = accF[mt][r]; psum += fv; psq += fv * fv; }
            }
        psum += __shfl_xor(psum, 16); psum += __shfl_xor(psum, 32);
        psq  += __shfl_xor(psq, 16);  psq  += __shfl_xor(psq, 32);
        const float m = psum * (1.f / 49.f);
        const float rstd = rsqrtf(psq * (1.f / 49.f) - m * m + EPS_LN);
#pragma unroll
        for (int mt = 0; mt < 4; ++mt)
#pragma unroll
            for (int r = 0; r < 4; ++r) {
                const int o = mt * 16 + l4 * 4 + r;
                float s = 0.f;
                if (o < 49) {
                    float y = bv3[128 + o] * (accF[mt][r] - m) * rstd + bv3[192 + o];
                    s = y * sigmoid_f(y);
                }
                sarr[mt * 4 + r] = s;
            }
    }
    __syncthreads();                                  // A2/X2 reads done

    // X3 = s (rows o, col pp), A3 = fx_w2
#pragma unroll
    for (int mt = 0; mt < 4; ++mt) {
        uint h0_ = pack2(sarr[4 * mt],     sarr[4 * mt + 1]);
        uint h1_ = pack2(sarr[4 * mt + 2], sarr[4 * mt + 3]);
        uint l0_ = pack2(sarr[4 * mt]     - __uint_as_float((h0_ & 0xffffu) << 16),
                         sarr[4 * mt + 1] - __uint_as_float(h0_ & 0xffff0000u));
        uint l1_ = pack2(sarr[4 * mt + 2] - __uint_as_float((h1_ & 0xffffu) << 16),
                         sarr[4 * mt + 3] - __uint_as_float(h1_ & 0xffff0000u));
        const int so = pp * 72 + mt * 16 + l4 * 4;
        *(uint2*)&Xh[so] = make_uint2(h0_, h1_);
        *(uint2*)&Xl[so] = make_uint2(l0_, l1_);
    }
    stage_wpad(fw2, 49, 49, 49, Ah, Al, tid);
    __syncthreads();

    f32x4 accG[4];
    gemm64(Ah, Al, Xh, Xl, bv3 + 64, lm, l4, pp, accG);   // bias fb2

    // gate + comb update + column sums -> pt[pp]
    {
        float tacc = 0.f;
#pragma unroll
        for (int mt = 0; mt < 4; ++mt)
#pragma unroll
            for (int r = 0; r < 4; ++r) {
                const int o = mt * 16 + l4 * 4 + r;
                if (o < 49) {
                    float gate = 1.f + sigmoid_f(accG[mt][r]);
                    float cx = comb[o * 64 + pp] * gate;   // unique (o,pp) per lane
                    comb[o * 64 + pp] = cx;
                    tacc += cx;
                }
            }
        tacc += __shfl_xor(tacc, 16); tacc += __shfl_xor(tacc, 32);
        if (l4 == 0) pt[pp] = tacc;
    }
    __syncthreads();
    const float inv = rcp_fast(pt[lane] + EPS_NORM);
    __syncthreads();   // all pt reads done -> bvP overlay safe

    // ---- stage op_w1 (over dead A strip) + bias vec; hides under P5 ----
    stage_w(w1, whiP, wloP, tid);
    if (tid < 64) { bvP[tid] = b1[tid]; bvP[64 + tid] = g[tid];
                    bvP[128 + tid] = be[tid]; bvP[192 + tid] = b2[tid]; }

    // ---- P5: weighted neighborhood reduction (haloB) ----
    const int c0 = uni(wv * 16);
    const int qq0 = c0 >> 3;
    float acc[16];
#pragma unroll
    for (int j = 0; j < 16; ++j) acc[j] = 0.f;
    for (int n = 0; n < 49; ++n) {
        int ryn = n / 7, rxn = n - ryn * 7;
        int rn = rbase + ryn * 13 + rxn;
        float cn = comb[n * 64 + lane] * inv;
        const int rb_ = rn << 6, rsw = rn & 7;
#pragma unroll
        for (int q = 0; q < 2; ++q) {
            uint4 v = *(const uint4*)&haloB[rb_ + (((qq0 + q) ^ rsw) << 3)];
            float2 a = up2(v.x), bb = up2(v.y), c = up2(v.z), d = up2(v.w);
            acc[8 * q + 0] += cn * a.x;  acc[8 * q + 1] += cn * a.y;
            acc[8 * q + 2] += cn * bb.x; acc[8 * q + 3] += cn * bb.y;
            acc[8 * q + 4] += cn * c.x;  acc[8 * q + 5] += cn * c.y;
            acc[8 * q + 6] += cn * d.x;  acc[8 * q + 7] += cn * d.y;
        }
    }
    __syncthreads();   // comb/haloB reads done; whiP/bvP staging visible

    // ---- P6a: write P5 result as split-bf16 activations [pixel][72] ----
    {
        uint hu[8], lu[8];
#pragma unroll
        for (int jj = 0; jj < 8; ++jj) {
            float x0 = act ? acc[2 * jj] : 0.f;
            float x1 = act ? acc[2 * jj + 1] : 0.f;
            uint hh = pack2(x0, x1);
            hu[jj] = hh;
            lu[jj] = pack2(x0 - __uint_as_float((hh & 0xffffu) << 16),
                           x1 - __uint_as_float(hh & 0xffff0000u));
        }
        const int rb = lane * 72 + c0;
        *(uint4*)&ahiP[rb]     = make_uint4(hu[0], hu[1], hu[2], hu[3]);
        *(uint4*)&ahiP[rb + 8] = make_uint4(hu[4], hu[5], hu[6], hu[7]);
        *(uint4*)&aloP[rb]     = make_uint4(lu[0], lu[1], lu[2], lu[3]);
        *(uint4*)&aloP[rb + 8] = make_uint4(lu[4], lu[5], lu[6], lu[7]);
    }
    __syncthreads();

    // ---- P6b: conv1 MFMA + LN(shfl) ----
    f32x4 f6[4];
    gemm64(whiP, wloP, ahiP, aloP, bvP, lm, l4, pp, f6);

    float psum = 0.f, psq = 0.f;
#pragma unroll
    for (int mt = 0; mt < 4; ++mt)
#pragma unroll
        for (int r = 0; r < 4; ++r) { float fv = f6[mt][r]; psum += fv; psq += fv * fv; }
    psum += __shfl_xor(psum, 16); psum += __shfl_xor(psum, 32);
    psq  += __shfl_xor(psq, 16);  psq  += __shfl_xor(psq, 32);
    const float m6 = psum * (1.f / 64.f);
    const float rstd6 = rsqrtf(psq * (1.f / 64.f) - m6 * m6 + EPS_LN);

    float yv[16];
#pragma unroll
    for (int mt = 0; mt < 4; ++mt)
#pragma unroll
        for (int r = 0; r < 4; ++r) {
            const int o = mt * 16 + l4 * 4 + r;
            yv[mt * 4 + r] = bvP[64 + o] * (f6[mt][r] - m6) * rstd6 + bvP[128 + o];
        }
    __syncthreads();   // conv1 fragment reads done -> strips reusable

    // write y (split bf16) over act strip; restage op_w2 over W strip
#pragma unroll
    for (int mt = 0; mt < 4; ++mt) {
        uint h0_ = pack2(yv[4 * mt],     yv[4 * mt + 1]);
        uint h1_ = pack2(yv[4 * mt + 2], yv[4 * mt + 3]);
        uint l0_ = pack2(yv[4 * mt]     - __uint_as_float((h0_ & 0xffffu) << 16),
                         yv[4 * mt + 1] - __uint_as_float(h0_ & 0xffff0000u));
        uint l1_ = pack2(yv[4 * mt + 2] - __uint_as_float((h1_ & 0xffffu) << 16),
                         yv[4 * mt + 3] - __uint_as_float(h1_ & 0xffff0000u));
        const int so = pp * 72 + mt * 16 + l4 * 4;
        *(uint2*)&ahiP[so] = make_uint2(h0_, h1_);
        *(uint2*)&aloP[so] = make_uint2(l0_, l1_);
    }
    stage_w(w2, whiP, wloP, tid);
    __syncthreads();

    // ---- P6c: conv2 MFMA + store ----
    f32x4 z6[4];
    gemm64(whiP, wloP, ahiP, aloP, bvP + 192, lm, l4, pp, z6);

    if (pp < 49) {
        const int py6 = div7s(pp), px6 = pp - py6 * 7;
        const int hwi6 = (ty * 7 + py6) * W + tx * 7 + px6;
#pragma unroll
        for (int mt = 0; mt < 4; ++mt)
#pragma unroll
            for (int r = 0; r < 4; ++r)
                out[(size_t)(b * 64 + mt * 16 + l4 * 4 + r) * HW + hwi6] = z6[mt][r];
    }
}

extern "C" void kernel_launch(void* const* d_in, const int* in_sizes, int n_in,
                              void* d_out, int out_size, void* d_ws, size_t ws_size,
                              hipStream_t stream)
{
    const float* spatial  = (const float*)d_in[0];
    const float* semantic = (const float*)d_in[1];
    const float* rp_w1 = (const float*)d_in[2];
    const float* rp_b1 = (const float*)d_in[3];
    const float* rp_g  = (const float*)d_in[4];
    const float* rp_be = (const float*)d_in[5];
    const float* rp_w2 = (const float*)d_in[6];
    const float* rp_b2 = (const float*)d_in[7];
    const float* fx_w1 = (const float*)d_in[8];
    const float* fx_b1 = (const float*)d_in[9];
    const float* fx_g  = (const float*)d_in[10];
    const float* fx_be = (const float*)d_in[11];
    const float* fx_w2 = (const float*)d_in[12];
    const float* fx_b2 = (const float*)d_in[13];
    const float* op_w1 = (const float*)d_in[14];
    const float* op_b1 = (const float*)d_in[15];
    const float* op_g  = (const float*)d_in[16];
    const float* op_be = (const float*)d_in[17];
    const float* op_w2 = (const float*)d_in[18];
    const float* op_b2 = (const float*)d_in[19];
    const float* sigma = (const float*)d_in[20];

    ushort* px16  = (ushort*)d_ws;                              // 3.21 MB
    float* sqnorm = (float*)((char*)d_ws + (size_t)NPIX * 64 * 2);

    k1_range_proj<<<NBLK, 256, 0, stream>>>(
        semantic, rp_w1, rp_b1, rp_g, rp_be, rp_w2, rp_b2, px16, sqnorm);
    k23_fused<<<NBLK, 256, 0, stream>>>(
        px16, sqnorm, semantic, spatial,
        fx_w1, fx_b1, fx_g, fx_be, fx_w2, fx_b2,
        op_w1, op_b1, op_g, op_be, op_w2, op_b2,
        sigma, (float*)d_out);
}

// Round 12
// 139.951 us; speedup vs baseline: 1.2593x; 1.0193x over previous
//
#include <hip/hip_runtime.h>

typedef unsigned short ushort;
typedef unsigned int uint;

constexpr int B = 2, C = 64, H = 112, W = 112;
constexpr int HW = H * W;          // 12544
constexpr int NPIX = B * HW;       // 25088
constexpr int NBLK = 512;          // 2 images x 16x16 tiles of 7x7 -> exactly 2 blocks/CU
constexpr float EPS_LN = 1e-6f, EPS_NORM = 1e-7f;

typedef __attribute__((ext_vector_type(8))) short bf16x8;   // 8 bf16 = 4 VGPRs
typedef __attribute__((ext_vector_type(4))) float f32x4;

__device__ __forceinline__ float rcp_fast(float x) { return __builtin_amdgcn_rcpf(x); }
__device__ __forceinline__ float sigmoid_f(float x) { return rcp_fast(1.f + __expf(-x)); }
__device__ __forceinline__ int uni(int x) { return __builtin_amdgcn_readfirstlane(x); }
__device__ __forceinline__ int div7s(int x)  { return (x * 9363) >> 16; }   // exact for 0<=x<64
__device__ __forceinline__ int div13s(int x) { return (x * 5042) >> 16; }   // exact for 0<=x<169

// f32 -> bf16 bits (round-nearest-even) + pair pack/unpack.
__device__ __forceinline__ ushort rne16(float x) {
    uint u = __float_as_uint(x);
    u += 0x7fffu + ((u >> 16) & 1u);
    return (ushort)(u >> 16);
}
__device__ __forceinline__ uint pack2(float a, float b) {
    return (uint)rne16(a) | ((uint)rne16(b) << 16);
}
__device__ __forceinline__ float2 up2(uint u) {
    return make_float2(__uint_as_float(u << 16), __uint_as_float(u & 0xffff0000u));
}
__device__ __forceinline__ float up1(ushort u) {
    return __uint_as_float((uint)u << 16);
}

__device__ __forceinline__ f32x4 mfma16(bf16x8 a, bf16x8 b, f32x4 c) {
    return __builtin_amdgcn_mfma_f32_16x16x32_bf16(a, b, c, 0, 0, 0);
}

// XCD-patch swizzle (BOTH kernels -> producer/consumer share an XCD L2).
__device__ __forceinline__ void decode_blk(int blk, int& b, int& ty, int& tx) {
    int p8 = blk & 7, i = blk >> 3;          // i in [0,64)
    b = p8 >> 2;
    int quad = p8 & 3;
    int lty = i >> 3, ltx = i & 7;           // 8x8 tiles per quadrant
    ty = (quad >> 1) * 8 + lty;              // [0,16)
    tx = (quad & 1) * 8 + ltx;
}

// ---------------------------------------------------------------------------
// Split-bf16 GEMM helpers. Weights/activations [64 rows][72] bf16 hi/lo.
// ---------------------------------------------------------------------------
__device__ __forceinline__ void stage_w(const float* __restrict__ wsrc,
                                        ushort* wh, ushort* wl, int tid)
{
#pragma unroll
    for (int i = 0; i < 8; ++i) {
        int idx2 = i * 256 + tid;            // 2048 float pairs = 64x64
        int o = idx2 >> 5, k = (idx2 & 31) * 2;
        float2 xy = *(const float2*)&wsrc[o * 64 + k];
        uint h = pack2(xy.x, xy.y);
        *(uint*)&wh[o * 72 + k] = h;
        *(uint*)&wl[o * 72 + k] = pack2(xy.x - __uint_as_float((h & 0xffffu) << 16),
                                        xy.y - __uint_as_float(h & 0xffff0000u));
    }
}

// Stage a nrow x ncol (<=64x64) matrix with arbitrary row stride into the
// zero-padded [64][72] hi/lo strips. thread t: row t>>2, col quarter t&3.
__device__ __forceinline__ void stage_wpad(const float* __restrict__ src, int ld,
                                           int nrow, int ncol,
                                           ushort* wh, ushort* wl, int tid)
{
    const int o = tid >> 2, q = (tid & 3) * 16;
#pragma unroll
    for (int jj = 0; jj < 8; ++jj) {
        int c = q + 2 * jj;
        float x0 = (o < nrow && c < ncol)     ? src[o * ld + c]     : 0.f;
        float x1 = (o < nrow && c + 1 < ncol) ? src[o * ld + c + 1] : 0.f;
        uint hh = pack2(x0, x1);
        uint ll = pack2(x0 - __uint_as_float((hh & 0xffffu) << 16),
                        x1 - __uint_as_float(hh & 0xffff0000u));
        *(uint*)&wh[o * 72 + c] = hh;
        *(uint*)&wl[o * 72 + c] = ll;
    }
}

__device__ __forceinline__ void gemm64_acc(const ushort* __restrict__ wh, const ushort* __restrict__ wl,
                                           const ushort* __restrict__ xh, const ushort* __restrict__ xl,
                                           int lm, int l4, int pp, f32x4 acc[4])
{
#pragma unroll
    for (int kt = 0; kt < 2; ++kt) {
        const int xo = pp * 72 + kt * 32 + l4 * 8;
        bf16x8 bh = *(const bf16x8*)&xh[xo];
        bf16x8 bl = *(const bf16x8*)&xl[xo];
#pragma unroll
        for (int mt = 0; mt < 4; ++mt) {
            const int wo = (mt * 16 + lm) * 72 + kt * 32 + l4 * 8;
            bf16x8 ah = *(const bf16x8*)&wh[wo];
            bf16x8 al = *(const bf16x8*)&wl[wo];
            acc[mt] = mfma16(al, bh, acc[mt]);
            acc[mt] = mfma16(ah, bl, acc[mt]);
            acc[mt] = mfma16(ah, bh, acc[mt]);
        }
    }
}

__device__ __forceinline__ void gemm64(const ushort* __restrict__ wh, const ushort* __restrict__ wl,
                                       const ushort* __restrict__ xh, const ushort* __restrict__ xl,
                                       const float* __restrict__ bias,
                                       int lm, int l4, int pp, f32x4 acc[4])
{
#pragma unroll
    for (int mt = 0; mt < 4; ++mt) {
        const int ob = mt * 16 + l4 * 4;
        acc[mt][0] = bias[ob]; acc[mt][1] = bias[ob + 1];
        acc[mt][2] = bias[ob + 2]; acc[mt][3] = bias[ob + 3];
    }
    gemm64_acc(wh, wl, xh, xl, lm, l4, pp, acc);
}

// ---------------------------------------------------------------------------
// k1: px = range_proj(semantic) -> px16[p][64] (bf16) + sqnorm[p].
// Unchanged from r7 (full split-bf16 MFMA; verified; ~7 us).
// ---------------------------------------------------------------------------
__global__ __launch_bounds__(256) void k1_range_proj(
    const float* __restrict__ sem,
    const float* __restrict__ w1, const float* __restrict__ b1,
    const float* __restrict__ g,  const float* __restrict__ be,
    const float* __restrict__ w2, const float* __restrict__ b2,
    ushort* __restrict__ px16, float* __restrict__ sqnorm)
{
    __shared__ __align__(16) ushort u16[28160];   // 56320 B
    ushort* wh1 = u16;                 // [64][72] each (4608 ushorts)
    ushort* wl1 = u16 + 4608;
    ushort* wh2 = u16 + 9216;
    ushort* wl2 = u16 + 13824;
    ushort* xh  = u16 + 18432;         // activations / s (reused)
    ushort* xl  = u16 + 23040;         // ..27648
    float*  bv  = (float*)(u16 + 27648);   // b1|g|be|b2 (256 floats)

    const int tid = threadIdx.x, lane = tid & 63, wv = tid >> 6;
    const int lm = lane & 15, l4 = lane >> 4;
    int b, ty, tx; decode_blk(blockIdx.x, b, ty, tx);

    {
        const int lp = lane < 49 ? lane : 48;
        const int py = div7s(lp), px = lp - py * 7;
        const int hw = (ty * 7 + py) * W + tx * 7 + px;
        const bool a = lane < 49;
        float xv[16];
#pragma unroll
        for (int j = 0; j < 16; ++j)
            xv[j] = a ? sem[(size_t)(b * 64 + wv * 16 + j) * HW + hw] : 0.f;
        uint hu[8], lu[8];
#pragma unroll
        for (int jj = 0; jj < 8; ++jj) {
            uint hh = pack2(xv[2 * jj], xv[2 * jj + 1]);
            hu[jj] = hh;
            lu[jj] = pack2(xv[2 * jj]     - __uint_as_float((hh & 0xffffu) << 16),
                           xv[2 * jj + 1] - __uint_as_float(hh & 0xffff0000u));
        }
        const int rb = lane * 72 + wv * 16;
        *(uint4*)&xh[rb]     = make_uint4(hu[0], hu[1], hu[2], hu[3]);
        *(uint4*)&xh[rb + 8] = make_uint4(hu[4], hu[5], hu[6], hu[7]);
        *(uint4*)&xl[rb]     = make_uint4(lu[0], lu[1], lu[2], lu[3]);
        *(uint4*)&xl[rb + 8] = make_uint4(lu[4], lu[5], lu[6], lu[7]);
    }
    stage_w(w1, wh1, wl1, tid);
    stage_w(w2, wh2, wl2, tid);
    if (tid < 64) { bv[tid] = b1[tid]; bv[64 + tid] = g[tid];
                    bv[128 + tid] = be[tid]; bv[192 + tid] = b2[tid]; }
    __syncthreads();

    const int pp = wv * 16 + lm;
    f32x4 f[4];
    gemm64(wh1, wl1, xh, xl, bv, lm, l4, pp, f);

    float psum = 0.f, psq = 0.f;
#pragma unroll
    for (int mt = 0; mt < 4; ++mt)
#pragma unroll
        for (int r = 0; r < 4; ++r) { float fv = f[mt][r]; psum += fv; psq += fv * fv; }
    psum += __shfl_xor(psum, 16); psum += __shfl_xor(psum, 32);
    psq  += __shfl_xor(psq, 16);  psq  += __shfl_xor(psq, 32);
    const float m = psum * (1.f / 64.f);
    const float rstd = rsqrtf(psq * (1.f / 64.f) - m * m + EPS_LN);

    float sv_[16];
#pragma unroll
    for (int mt = 0; mt < 4; ++mt)
#pragma unroll
        for (int r = 0; r < 4; ++r) {
            const int o = mt * 16 + l4 * 4 + r;
            float y = bv[64 + o] * (f[mt][r] - m) * rstd + bv[128 + o];
            sv_[mt * 4 + r] = y * sigmoid_f(y);
        }
    __syncthreads();
#pragma unroll
    for (int mt = 0; mt < 4; ++mt) {
        uint h0 = pack2(sv_[4 * mt],     sv_[4 * mt + 1]);
        uint h1 = pack2(sv_[4 * mt + 2], sv_[4 * mt + 3]);
        uint l0 = pack2(sv_[4 * mt]     - __uint_as_float((h0 & 0xffffu) << 16),
                        sv_[4 * mt + 1] - __uint_as_float(h0 & 0xffff0000u));
        uint l1 = pack2(sv_[4 * mt + 2] - __uint_as_float((h1 & 0xffffu) << 16),
                        sv_[4 * mt + 3] - __uint_as_float(h1 & 0xffff0000u));
        const int so = pp * 72 + mt * 16 + l4 * 4;
        *(uint2*)&xh[so] = make_uint2(h0, h1);
        *(uint2*)&xl[so] = make_uint2(l0, l1);
    }
    __syncthreads();

    f32x4 z[4];
    gemm64(wh2, wl2, xh, xl, bv + 192, lm, l4, pp, z);

    float sq = 0.f;
#pragma unroll
    for (int mt = 0; mt < 4; ++mt)
#pragma unroll
        for (int r = 0; r < 4; ++r) sq += z[mt][r] * z[mt][r];
    sq += __shfl_xor(sq, 16); sq += __shfl_xor(sq, 32);

    if (pp < 49) {
        const int py = div7s(pp), px = pp - py * 7;
        const int hwi = (ty * 7 + py) * W + tx * 7 + px;
        ushort* dst = &px16[((size_t)b * HW + hwi) * 64];
#pragma unroll
        for (int mt = 0; mt < 4; ++mt)
            *(uint2*)&dst[mt * 16 + l4 * 4] =
                make_uint2(pack2(z[mt][0], z[mt][1]), pack2(z[mt][2], z[mt][3]));
        if (l4 == 0) sqnorm[(size_t)b * HW + hwi] = sq;
    }
}

// ---------------------------------------------------------------------------
// k23 (r12): r11 + two latency changes.
// (1) dmat stored bf16 [176][66] at fl [5408,11216) — frees [12640,18048)
//     during Phase A. exp-arg perturbation ~2.5e-5, invisible vs the bf16
//     halo quantization. Halves P2 LDS write traffic.
// (2) haloB (spat, ~43 KB global reads — biggest traffic block) stages at
//     kernel ENTRY into [12640,18048), hidden under P1 + P2 + extraction.
// Plus: P5 runtime n/7 -> nested ryn/rxn loops (division-free, unrolled).
// ---------------------------------------------------------------------------
__global__ __launch_bounds__(256, 2) void k23_fused(
    const ushort* __restrict__ px16, const float* __restrict__ sqnorm,
    const float* __restrict__ sem,  const float* __restrict__ spat,
    const float* __restrict__ fw1, const float* __restrict__ fb1,
    const float* __restrict__ fg,  const float* __restrict__ fbe,
    const float* __restrict__ fw2, const float* __restrict__ fb2,
    const float* __restrict__ w1, const float* __restrict__ b1,
    const float* __restrict__ g,  const float* __restrict__ be,
    const float* __restrict__ w2, const float* __restrict__ b2,
    const float* __restrict__ sigma_, float* __restrict__ out)
{
    __shared__ __align__(16) float smem[18048];          // 72192 B arena
    // Phase A:
    ushort* haloA  = (ushort*)smem;                      // [169][64] bf16 fl [0,5408)
    ushort* dmat16 = (ushort*)(smem + 5408);             // [176][66] bf16 fl [5408,11216)
    float*  sqn_l  = smem + 11216;                       // 169 fl [11216,11385)
    ushort* haloB  = (ushort*)(smem + 12640);            // [169][64] bf16 fl [12640,18048) — staged at ENTRY
    // post-extraction overlays (haloA/dmat16/sqn dead):
    float*  comb  = smem;                                // 3136 fl [0,3136)
    float*  bv3   = smem + 3136;                         // 256: fb1|fb2|fg|fbe
    float*  pt    = smem + 3136;                         // 64 (overlays dead fb1)
    ushort* Xh    = (ushort*)(smem + 3392);              // [64][72] fl [3392,5696)
    ushort* Xl    = (ushort*)(smem + 5696);              // fl [5696,8000)
    ushort* Ah    = (ushort*)(smem + 8000);              // fl [8000,10304)
    ushort* Al    = (ushort*)(smem + 10304);             // fl [10304,12608)
    // P5/P6 overlays:
    float*  bvP   = smem + 3136;                         // 256 (pt/bv3 dead)
    ushort* whiP  = (ushort*)(smem + 8000);              // over A strip
    ushort* wloP  = (ushort*)(smem + 10304);
    ushort* ahiP  = (ushort*)(smem + 3392);              // over X strip
    ushort* aloP  = (ushort*)(smem + 5696);

    const int tid = threadIdx.x, lane = tid & 63, wv = tid >> 6;
    const int lm = lane & 15, l4 = lane >> 4;
    int b, ty, tx; decode_blk(blockIdx.x, b, ty, tx);
    const int lp  = lane < 49 ? lane : 48;
    const int py  = div7s(lp), pxl = lp - py * 7;
    const int h = ty * 7 + py, w = tx * 7 + pxl;
    const int hw = h * W + w;
    const int h0 = ty * 7 - 3, w0 = tx * 7 - 3;
    const bool act = lane < 49;
    const int pp = wv * 16 + lm;

    // ---- sv16 prefetch: this thread's 16-channel slice (X2 staging) ----
    float sv16[16];
#pragma unroll
    for (int j = 0; j < 16; ++j)
        sv16[j] = sem[(size_t)(b * 64 + wv * 16 + j) * HW + hw];

    // ---- haloB staging at ENTRY: latency hides under P1+P2+extraction ----
    if (tid < 169) {
        const int ry = div13s(tid), rx = tid - ry * 13;
        const int hh = h0 + ry, ww = w0 + rx;
        const bool valid = (unsigned)hh < (unsigned)H && (unsigned)ww < (unsigned)W;
        const int soff = hh * W + ww;
        const int rsw = (tid & 7), rb_ = tid << 6;
#pragma unroll
        for (int cq = 0; cq < 8; ++cq) {
            uint4 v = make_uint4(0u, 0u, 0u, 0u);
            if (valid) {
                const float* sp = &spat[(size_t)(b * 64 + 8 * cq) * HW + soff];
                v.x = pack2(sp[0],      sp[HW]);
                v.y = pack2(sp[2 * HW], sp[3 * HW]);
                v.z = pack2(sp[4 * HW], sp[5 * HW]);
                v.w = pack2(sp[6 * HW], sp[7 * HW]);
            }
            *(uint4*)&haloB[rb_ + ((cq ^ rsw) << 3)] = v;
        }
    }

    // ---- P1: stage px halo -> haloA (bf16): 1352 16-B loads ----
    for (int i = 0; i < 6; ++i) {
        int idx = i * 256 + tid;
        if (idx < 1352) {
            int r = idx >> 3, q = idx & 7;
            int ry = div13s(r), rx = r - ry * 13;
            int hh = h0 + ry, ww = w0 + rx;
            bool valid = (unsigned)hh < (unsigned)H && (unsigned)ww < (unsigned)W;
            uint4 v = make_uint4(0u, 0u, 0u, 0u);
            if (valid) v = *(const uint4*)&px16[((size_t)b * HW + hh * W + ww) * 64 + 8 * q];
            *(uint4*)&haloA[(r << 6) + ((q ^ (r & 7)) << 3)] = v;
        }
    }
    if (tid < 169) {
        int ry = div13s(tid), rx = tid - ry * 13;
        int hh = h0 + ry, ww = w0 + rx;
        bool valid = (unsigned)hh < (unsigned)H && (unsigned)ww < (unsigned)W;
        float v = 0.f;
        if (valid) v = sqnorm[(size_t)b * HW + hh * W + ww];
        sqn_l[tid] = v;
    }
    __syncthreads();

    // ---- P2-MFMA: D[hp][p] = <haloA[hp], haloA[rp(p)]> -> dmat16 (bf16) ----
    {
        const int qp = pp < 49 ? pp : 48;
        const int pyp = div7s(qp), pxp = qp - pyp * 7;
        const int rpp = pyp * 13 + pxp + 42;
        bf16x8 bc0 = *(const bf16x8*)&haloA[(rpp << 6) + ((l4 ^ (rpp & 7)) << 3)];
        bf16x8 bc1 = *(const bf16x8*)&haloA[(rpp << 6) + (((4 + l4) ^ (rpp & 7)) << 3)];
#pragma unroll
        for (int mt = 0; mt < 11; ++mt) {
            const int r = mt * 16 + lm;
            bf16x8 a0 = *(const bf16x8*)&haloA[(r << 6) + ((l4 ^ (r & 7)) << 3)];
            bf16x8 a1 = *(const bf16x8*)&haloA[(r << 6) + (((4 + l4) ^ (r & 7)) << 3)];
            f32x4 d = {0.f, 0.f, 0.f, 0.f};
            d = mfma16(a0, bc0, d);
            d = mfma16(a1, bc1, d);
            const int orow = mt * 16 + l4 * 4;
#pragma unroll
            for (int rr = 0; rr < 4; ++rr)
                dmat16[(orow + rr) * 66 + pp] = rne16(d[rr]);
        }
    }
    __syncthreads();

    // ---- extraction (wave-split n) into regs ----
    const int rbase = py * 13 + pxl;
    const int rp = rbase + 42;
    float cbl[13];
    {
        const float sqc = sqn_l[rp];
        const float sg_ = sigma_[0];
        const float inv2s2 = rcp_fast(2.f * sg_ * sg_);
#pragma unroll
        for (int i = 0; i < 13; ++i) {
            const int n = uni(wv + 4 * i);
            cbl[i] = 0.f;
            if (n < 49) {
                int ryn = div7s(n), rxn = n - ryn * 7;
                int dy = ryn - 3, dx = rxn - 3;
                int rn = rbase + ryn * 13 + rxn;
                float dot = up1(dmat16[rn * 66 + lane]);
                float dist2 = fmaxf(sqn_l[rn] + sqc - 2.f * dot, 0.f);
                bool validn = (unsigned)(h + dy) < (unsigned)H && (unsigned)(w + dx) < (unsigned)W;
                float d2n = (float)(dy * dy + dx * dx);
                cbl[i] = validn ? __expf(-(dist2 * (1.f / 128.f) + d2n * inv2s2)) : 0.f;
            }
        }
    }
    __syncthreads();   // dmat16/haloA/sqn dead below

    // ---- post-extraction staging: comb f32 + X1(comb bf16) + A1 + bv3 ----
#pragma unroll
    for (int i = 0; i < 13; ++i) {
        const int n = wv + 4 * i;
        if (n < 49) {
            float v = cbl[i];
            comb[n * 64 + lane] = v;
            ushort hh = rne16(v);
            Xh[lane * 72 + n] = hh;
            Xl[lane * 72 + n] = rne16(v - up1(hh));
        }
    }
    if (tid < 64) {
#pragma unroll
        for (int r = 49; r < 64; ++r) { Xh[tid * 72 + r] = 0; Xl[tid * 72 + r] = 0; }
        bv3[tid]       = (tid < 49) ? fb1[tid] : 0.f;
        bv3[64 + tid]  = (tid < 49) ? fb2[tid] : 0.f;
        bv3[128 + tid] = (tid < 49) ? fg[tid]  : 0.f;
        bv3[192 + tid] = (tid < 49) ? fbe[tid] : 0.f;
    }
    stage_wpad(fw1, 113, 49, 49, Ah, Al, tid);   // A1 = comb-half of fx_w1
    __syncthreads();

    // ---- P3-MFMA: conv1 = A1*X1 + A2*X2, conv2 = A3*X3 ----
    f32x4 accF[4];
    gemm64(Ah, Al, Xh, Xl, bv3, lm, l4, pp, accF);   // bias fb1 + comb part
    __syncthreads();                                  // A1/X1 reads done

    // X2 = sem (from sv16), A2 = sem-half of fx_w1
    {
        uint hu[8], lu[8];
#pragma unroll
        for (int jj = 0; jj < 8; ++jj) {
            float x0 = sv16[2 * jj], x1 = sv16[2 * jj + 1];
            uint hh = pack2(x0, x1);
            hu[jj] = hh;
            lu[jj] = pack2(x0 - __uint_as_float((hh & 0xffffu) << 16),
                           x1 - __uint_as_float(hh & 0xffff0000u));
        }
        const int rb = lane * 72 + wv * 16;
        *(uint4*)&Xh[rb]     = make_uint4(hu[0], hu[1], hu[2], hu[3]);
        *(uint4*)&Xh[rb + 8] = make_uint4(hu[4], hu[5], hu[6], hu[7]);
        *(uint4*)&Xl[rb]     = make_uint4(lu[0], lu[1], lu[2], lu[3]);
        *(uint4*)&Xl[rb + 8] = make_uint4(lu[4], lu[5], lu[6], lu[7]);
    }
    stage_wpad(fw1 + 49, 113, 49, 64, Ah, Al, tid);
    __syncthreads();

    gemm64_acc(Ah, Al, Xh, Xl, lm, l4, pp, accF);    // += sem part

    // LN over o<49 (shfl across l4-groups) + SiLU -> s in regs
    float sarr[16];
    {
        float psum = 0.f, psq = 0.f;
#pragma unroll
        for (int mt = 0; mt < 4; ++mt)
#pragma unroll
            for (int r = 0; r < 4; ++r) {
                const int o = mt * 16 + l4 * 4 + r;
                if (o < 49) { float fv = accF[mt][r]; psum += fv; psq += fv * fv; }
            }
        psum += __shfl_xor(psum, 16); psum += __shfl_xor(psum, 32);
        psq  += __shfl_xor(psq, 16);  psq  += __shfl_xor(psq, 32);
        const float m = psum * (1.f / 49.f);
        const float rstd = rsqrtf(psq * (1.f / 49.f) - m * m + EPS_LN);
#pragma unroll
        for (int mt = 0; mt < 4; ++mt)
#pragma unroll
            for (int r = 0; r < 4; ++r) {
                const int o = mt * 16 + l4 * 4 + r;
                float s = 0.f;
                if (o < 49) {
                    float y = bv3[128 + o] * (accF[mt][r] - m) * rstd + bv3[192 + o];
                    s = y * sigmoid_f(y);
                }
                sarr[mt * 4 + r] = s;
            }
    }
    __syncthreads();                                  // A2/X2 reads done

    // X3 = s (rows o, col pp), A3 = fx_w2
#pragma unroll
    for (int mt = 0; mt < 4; ++mt) {
        uint h0_ = pack2(sarr[4 * mt],     sarr[4 * mt + 1]);
        uint h1_ = pack2(sarr[4 * mt + 2], sarr[4 * mt + 3]);
        uint l0_ = pack2(sarr[4 * mt]     - __uint_as_float((h0_ & 0xffffu) << 16),
                         sarr[4 * mt + 1] - __uint_as_float(h0_ & 0xffff0000u));
        uint l1_ = pack2(sarr[4 * mt + 2] - __uint_as_float((h1_ & 0xffffu) << 16),
                         sarr[4 * mt + 3] - __uint_as_float(h1_ & 0xffff0000u));
        const int so = pp * 72 + mt * 16 + l4 * 4;
        *(uint2*)&Xh[so] = make_uint2(h0_, h1_);
        *(uint2*)&Xl[so] = make_uint2(l0_, l1_);
    }
    stage_wpad(fw2, 49, 49, 49, Ah, Al, tid);
    __syncthreads();

    f32x4 accG[4];
    gemm64(Ah, Al, Xh, Xl, bv3 + 64, lm, l4, pp, accG);   // bias fb2

    // gate + comb update + column sums -> pt[pp]
    {
        float tacc = 0.f;
#pragma unroll
        for (int mt = 0; mt < 4; ++mt)
#pragma unroll
            for (int r = 0; r < 4; ++r) {
                const int o = mt * 16 + l4 * 4 + r;
                if (o < 49) {
                    float gate = 1.f + sigmoid_f(accG[mt][r]);
                    float cx = comb[o * 64 + pp] * gate;   // unique (o,pp) per lane
                    comb[o * 64 + pp] = cx;
                    tacc += cx;
                }
            }
        tacc += __shfl_xor(tacc, 16); tacc += __shfl_xor(tacc, 32);
        if (l4 == 0) pt[pp] = tacc;
    }
    __syncthreads();
    const float inv = rcp_fast(pt[lane] + EPS_NORM);
    __syncthreads();   // all pt reads done -> bvP overlay safe

    // ---- stage op_w1 (over dead A strip) + bias vec; hides under P5 ----
    stage_w(w1, whiP, wloP, tid);
    if (tid < 64) { bvP[tid] = b1[tid]; bvP[64 + tid] = g[tid];
                    bvP[128 + tid] = be[tid]; bvP[192 + tid] = b2[tid]; }

    // ---- P5: weighted neighborhood reduction (haloB, staged at entry) ----
    const int c0 = uni(wv * 16);
    const int qq0 = c0 >> 3;
    float acc[16];
#pragma unroll
    for (int j = 0; j < 16; ++j) acc[j] = 0.f;
    for (int ryn = 0; ryn < 7; ++ryn) {
#pragma unroll
        for (int rxn = 0; rxn < 7; ++rxn) {
            const int n = ryn * 7 + rxn;
            const int rn = rbase + ryn * 13 + rxn;
            float cn = comb[n * 64 + lane] * inv;
            const int rb_ = rn << 6, rsw = rn & 7;
#pragma unroll
            for (int q = 0; q < 2; ++q) {
                uint4 v = *(const uint4*)&haloB[rb_ + (((qq0 + q) ^ rsw) << 3)];
                float2 a = up2(v.x), bb = up2(v.y), c = up2(v.z), d = up2(v.w);
                acc[8 * q + 0] += cn * a.x;  acc[8 * q + 1] += cn * a.y;
                acc[8 * q + 2] += cn * bb.x; acc[8 * q + 3] += cn * bb.y;
                acc[8 * q + 4] += cn * c.x;  acc[8 * q + 5] += cn * c.y;
                acc[8 * q + 6] += cn * d.x;  acc[8 * q + 7] += cn * d.y;
            }
        }
    }
    __syncthreads();   // comb/haloB reads done; whiP/bvP staging visible

    // ---- P6a: write P5 result as split-bf16 activations [pixel][72] ----
    {
        uint hu[8], lu[8];
#pragma unroll
        for (int jj = 0; jj < 8; ++jj) {
            float x0 = act ? acc[2 * jj] : 0.f;
            float x1 = act ? acc[2 * jj + 1] : 0.f;
            uint hh = pack2(x0, x1);
            hu[jj] = hh;
            lu[jj] = pack2(x0 - __uint_as_float((hh & 0xffffu) << 16),
                           x1 - __uint_as_float(hh & 0xffff0000u));
        }
        const int rb = lane * 72 + c0;
        *(uint4*)&ahiP[rb]     = make_uint4(hu[0], hu[1], hu[2], hu[3]);
        *(uint4*)&ahiP[rb + 8] = make_uint4(hu[4], hu[5], hu[6], hu[7]);
        *(uint4*)&aloP[rb]     = make_uint4(lu[0], lu[1], lu[2], lu[3]);
        *(uint4*)&aloP[rb + 8] = make_uint4(lu[4], lu[5], lu[6], lu[7]);
    }
    __syncthreads();

    // ---- P6b: conv1 MFMA + LN(shfl) ----
    f32x4 f6[4];
    gemm64(whiP, wloP, ahiP, aloP, bvP, lm, l4, pp, f6);

    float psum = 0.f, psq = 0.f;
#pragma unroll
    for (int mt = 0; mt < 4; ++mt)
#pragma unroll
        for (int r = 0; r < 4; ++r) { float fv = f6[mt][r]; psum += fv; psq += fv * fv; }
    psum += __shfl_xor(psum, 16); psum += __shfl_xor(psum, 32);
    psq  += __shfl_xor(psq, 16);  psq  += __shfl_xor(psq, 32);
    const float m6 = psum * (1.f / 64.f);
    const float rstd6 = rsqrtf(psq * (1.f / 64.f) - m6 * m6 + EPS_LN);

    float yv[16];
#pragma unroll
    for (int mt = 0; mt < 4; ++mt)
#pragma unroll
        for (int r = 0; r < 4; ++r) {
            const int o = mt * 16 + l4 * 4 + r;
            yv[mt * 4 + r] = bvP[64 + o] * (f6[mt][r] - m6) * rstd6 + bvP[128 + o];
        }
    __syncthreads();   // conv1 fragment reads done -> strips reusable

    // write y (split bf16) over act strip; restage op_w2 over W strip
#pragma unroll
    for (int mt = 0; mt < 4; ++mt) {
        uint h0_ = pack2(yv[4 * mt],     yv[4 * mt + 1]);
        uint h1_ = pack2(yv[4 * mt + 2], yv[4 * mt + 3]);
        uint l0_ = pack2(yv[4 * mt]     - __uint_as_float((h0_ & 0xffffu) << 16),
                         yv[4 * mt + 1] - __uint_as_float(h0_ & 0xffff0000u));
        uint l1_ = pack2(yv[4 * mt + 2] - __uint_as_float((h1_ & 0xffffu) << 16),
                         yv[4 * mt + 3] - __uint_as_float(h1_ & 0xffff0000u));
        const int so = pp * 72 + mt * 16 + l4 * 4;
        *(uint2*)&ahiP[so] = make_uint2(h0_, h1_);
        *(uint2*)&aloP[so] = make_uint2(l0_, l1_);
    }
    stage_w(w2, whiP, wloP, tid);
    __syncthreads();

    // ---- P6c: conv2 MFMA + store ----
    f32x4 z6[4];
    gemm64(whiP, wloP, ahiP, aloP, bvP + 192, lm, l4, pp, z6);

    if (pp < 49) {
        const int py6 = div7s(pp), px6 = pp - py6 * 7;
        const int hwi6 = (ty * 7 + py6) * W + tx * 7 + px6;
#pragma unroll
        for (int mt = 0; mt < 4; ++mt)
#pragma unroll
            for (int r = 0; r < 4; ++r)
                out[(size_t)(b * 64 + mt * 16 + l4 * 4 + r) * HW + hwi6] = z6[mt][r];
    }
}

extern "C" void kernel_launch(void* const* d_in, const int* in_sizes, int n_in,
                              void* d_out, int out_size, void* d_ws, size_t ws_size,
                              hipStream_t stream)
{
    const float* spatial  = (const float*)d_in[0];
    const float* semantic = (const float*)d_in[1];
    const float* rp_w1 = (const float*)d_in[2];
    const float* rp_b1 = (const float*)d_in[3];
    const float* rp_g  = (const float*)d_in[4];
    const float* rp_be = (const float*)d_in[5];
    const float* rp_w2 = (const float*)d_in[6];
    const float* rp_b2 = (const float*)d_in[7];
    const float* fx_w1 = (const float*)d_in[8];
    const float* fx_b1 = (const float*)d_in[9];
    const float* fx_g  = (const float*)d_in[10];
    const float* fx_be = (const float*)d_in[11];
    const float* fx_w2 = (const float*)d_in[12];
    const float* fx_b2 = (const float*)d_in[13];
    const float* op_w1 = (const float*)d_in[14];
    const float* op_b1 = (const float*)d_in[15];
    const float* op_g  = (const float*)d_in[16];
    const float* op_be = (const float*)d_in[17];
    const float* op_w2 = (const float*)d_in[18];
    const float* op_b2 = (const float*)d_in[19];
    const float* sigma = (const float*)d_in[20];

    ushort* px16  = (ushort*)d_ws;                              // 3.21 MB
    float* sqnorm = (float*)((char*)d_ws + (size_t)NPIX * 64 * 2);

    k1_range_proj<<<NBLK, 256, 0, stream>>>(
        semantic, rp_w1, rp_b1, rp_g, rp_be, rp_w2, rp_b2, px16, sqnorm);
    k23_fused<<<NBLK, 256, 0, stream>>>(
        px16, sqnorm, semantic, spatial,
        fx_w1, fx_b1, fx_g, fx_be, fx_w2, fx_b2,
        op_w1, op_b1, op_g, op_be, op_w2, op_b2,
        sigma, (float*)d_out);
}